// Round 11
// baseline (781.751 us; speedup 1.0000x reference)
//
#include <hip/hip_runtime.h>
#include <hip/hip_bf16.h>

// ---- problem constants ----
#define BSZ 4
#define TT 64
#define NNODE 128
#define NFEAT 16
#define HIDD 64
#define NHEAD 4
#define RHID 256
#define LDIM 64
#define EPG 1024
#define NGRAPH (BSZ*TT)          // 256
#define NTOT (NGRAPH*NNODE)      // 32768
#define ESLOTS (EPG+NNODE)       // 1152

// ---- canonical fp32 weight buffer offsets (floats) ----
#define WOFF_G0W 0
#define WOFF_G0AS 4096
#define WOFF_G0AD 4352
#define WOFF_G0B 4608
#define WOFF_G1W 4864
#define WOFF_G1AS 70400
#define WOFF_G1AD 70656
#define WOFF_G1B 70912
#define WOFF_G2W 71168
#define WOFF_G2AS 87552
#define WOFF_G2AD 87616
#define WOFF_G2B 87680
#define WOFF_WIHF 87744
#define WOFF_WHHF 153280
#define WOFF_BIHF 415424
#define WOFF_BHHF 416448
#define WOFF_WIHB 417472
#define WOFF_WHHB 483008
#define WOFF_BIHB 745152
#define WOFF_BHHB 746176
#define WOFF_MUW 747200
#define WOFF_MUB 779968
#define WOFF_LVW 780032
#define WOFF_LVB 812800
#define WTOTAL   812864

// ---- workspace float offsets ----
#define FOFF_WBUF 4096
#define FOFF_WE   1576960      // WT (f16-pair Whh, 262144 uints)
#define FOFF_BBF  1900000      // bf16 B matrices (u16 view)
#define FOFF_XFP  2756608
#define FOFF_XBP  3018752
#define FOFF_HT   3280896
#define FOFF_XSEQ 3282944
#define FOFF_P    7485440

// bf16 B-matrix u16 offsets inside BBF
#define BOFF_G0 0
#define BOFF_G1 4096
#define BOFF_G2 69632
#define BOFF_WF 86016
#define BOFF_WB 151552
#define BTOTAL  217088

// setup phases
#define SP_CVTX  (WTOTAL + BTOTAL)            // 1029952
#define SP_WHH   (SP_CVTX + NTOT*NFEAT)       // 1554240
#define SP_TOTAL (SP_WHH + 262144)            // 1816384

typedef __attribute__((ext_vector_type(8))) short short8;
typedef __attribute__((ext_vector_type(4))) float float4v;

__device__ __forceinline__ float b2f(unsigned short u){
  union { unsigned int i; float f; } v; v.i = ((unsigned int)u) << 16; return v.f;
}
__device__ __forceinline__ unsigned short f2b(float f){
  __hip_bfloat16 h = __float2bfloat16(f);
  union { __hip_bfloat16 h; unsigned short u; } v; v.h = h; return v.u;
}
__device__ __forceinline__ float ldf(const void* p, int i, int flag){
  return flag ? b2f(((const unsigned short*)p)[i]) : ((const float*)p)[i];
}

// fused half2 dot: acc += w.x*h.x + w.y*h.y
__device__ __forceinline__ float dot2h(unsigned int w, unsigned int h, float acc){
#if __has_builtin(__builtin_amdgcn_fdot2)
  typedef _Float16 h2v __attribute__((ext_vector_type(2)));
  union { unsigned int u; h2v v; } a, b; a.u = w; b.u = h;
  return __builtin_amdgcn_fdot2(a.v, b.v, acc, false);
#else
  union { unsigned int u; _Float16 h[2]; } a, b; a.u = w; b.u = h;
  return acc + (float)a.h[0] * (float)b.h[0] + (float)a.h[1] * (float)b.h[1];
#endif
}

// ---------------- dtype sniff ----------------
__global__ void sniff_kernel(const unsigned short* __restrict__ w, int* __restrict__ flag){
  __shared__ int cnt;
  if (threadIdx.x == 0) cnt = 0;
  __syncthreads();
  int ok = 0;
  for (int i = threadIdx.x; i < 2048; i += 256){
    float a = fabsf(b2f(w[2 * i]));
    if (a > 1e-8f && a < 4.f) ok++;
  }
  atomicAdd(&cnt, ok);
  __syncthreads();
  if (threadIdx.x == 0) *flag = (cnt >= 1024) ? 1 : 0;
}

// ---------------- fused setup: cvtw + packb + cvtx + packwhh ----------------
struct CvtArgs {
  const void* src[24];
  int off[25];
};
__global__ void setup_kernel(CvtArgs a, const int* __restrict__ flag,
                             float* __restrict__ W, unsigned short* __restrict__ BBF,
                             unsigned short* __restrict__ P, unsigned int* __restrict__ WT,
                             const void* __restrict__ x)
{
  int id = blockIdx.x * blockDim.x + threadIdx.x;
  if (id >= SP_TOTAL) return;
  int fl = *flag;
  if (id < WTOTAL){
    int k = 0;
    while (id >= a.off[k + 1]) ++k;
    W[id] = ldf(a.src[k], id - a.off[k], fl);
  } else if (id < WTOTAL + BTOTAL){
    int r = id - WTOTAL;
    float v;
    if (r < BOFF_G1)       v = ldf(a.src[0], r, fl);
    else if (r < BOFF_G2)  v = ldf(a.src[4], r - BOFF_G1, fl);
    else if (r < BOFF_WF)  v = ldf(a.src[8], r - BOFF_G2, fl);
    else if (r < BOFF_WB){ int q = r - BOFF_WF; int k = q >> 10, n = q & 1023;
                           v = ldf(a.src[12], n * 64 + k, fl); }
    else                 { int q = r - BOFF_WB; int k = q >> 10, n = q & 1023;
                           v = ldf(a.src[16], n * 64 + k, fl); }
    BBF[r] = f2b(v);
  } else if (id < SP_CVTX + NTOT * NFEAT){
    int r = id - SP_CVTX;
    P[r] = fl ? ((const unsigned short*)x)[r] : f2b(((const float*)x)[r]);
  } else {
    int r0 = id - SP_WHH;                 // < 262144
    int d = r0 >> 17;
    int r = r0 & 131071;
    int c = r & 3;
    int u = (r >> 2) & 1023;
    int kk4 = r >> 12;
    int kk = kk4 * 4 + c;
    const void* Wsrc = d ? a.src[17] : a.src[13];   // Whh_b / Whh_f raw
    _Float16 va = (_Float16)ldf(Wsrc, u * RHID + 2 * kk, fl);
    _Float16 vb = (_Float16)ldf(Wsrc, u * RHID + 2 * kk + 1, fl);
    union { _Float16 h; unsigned short s; } ua, ub; ua.h = va; ub.h = vb;
    WT[r0] = (unsigned int)ua.s | ((unsigned int)ub.s << 16);
  }
}

// ---------------- CSR build ----------------
__global__ void csr_kernel(const int* __restrict__ ei, int* __restrict__ row,
                           int* __restrict__ colsrc, int* __restrict__ coldst){
  __shared__ int cnt[NNODE];
  __shared__ int off[NNODE];
  int tid = threadIdx.x;
  for (int i = tid; i < NNODE; i += blockDim.x) cnt[i] = 0;
  __syncthreads();
  for (int i = tid; i < ESLOTS; i += blockDim.x){
    int d = (i < EPG) ? ei[EPG + i] : (i - EPG);
    atomicAdd(&cnt[d], 1);
  }
  __syncthreads();
  if (tid == 0){
    int acc = 0;
    for (int i = 0; i < NNODE; ++i){ row[i] = acc; off[i] = acc; acc += cnt[i]; }
    row[NNODE] = acc;
  }
  __syncthreads();
  for (int i = tid; i < ESLOTS; i += blockDim.x){
    int s, d;
    if (i < EPG){ s = ei[i]; d = ei[EPG + i]; } else { s = i - EPG; d = i - EPG; }
    int pos = atomicAdd(&off[d], 1);
    colsrc[pos] = s; coldst[pos] = d;
  }
}

// ---------------- fused 3-layer GAT + pool: one block per graph ----------------
__global__ __launch_bounds__(256, 1)
void gatall_kernel(const unsigned short* __restrict__ X,
                   const unsigned short* __restrict__ BBF,
                   const float* __restrict__ Wbuf,
                   const int* __restrict__ csr_row, const int* __restrict__ csr_src,
                   unsigned short* __restrict__ XSEQ)
{
  __shared__ unsigned short HAs[128 * 264];
  __shared__ unsigned short HBs[128 * 264];
  __shared__ unsigned short Bst[128 * 40];
  __shared__ unsigned short AWs[1152 * 4];
  __shared__ float ALSs[512];
  __shared__ float ALDs[512];
  __shared__ int   rowL[132];
  __shared__ unsigned short srcL[1152];

  const int tid = threadIdx.x;
  const int g = blockIdx.x;
  const int w = tid >> 6, lane = tid & 63, q = lane >> 4, r = lane & 15;

  for (int i = tid; i < 129; i += 256) rowL[i] = csr_row[i];
  for (int i = tid; i < 1152; i += 256) srcL[i] = (unsigned short)csr_src[i];

  float4v acc0[16], acc1[16];

  //======== Layer 0 GEMM ========
  #pragma unroll
  for (int i = 0; i < 16; ++i){ acc0[i] = (float4v){0,0,0,0}; acc1[i] = (float4v){0,0,0,0}; }
  short8 xa0 = {0,0,0,0,0,0,0,0}, xa1 = {0,0,0,0,0,0,0,0};
  if (q < 2){
    xa0 = *(const short8*)(X + ((size_t)(g * 128 + 16 * w       + r)) * 16 + q * 8);
    xa1 = *(const short8*)(X + ((size_t)(g * 128 + 16 * (w + 4) + r)) * 16 + q * 8);
  }
  for (int nh = 0; nh < 2; ++nh){
    __syncthreads();
    #pragma unroll
    for (int p = 0; p < 2; ++p){
      int k2 = tid >> 3, c = (tid & 7) * 8;
      uint4 v = {0,0,0,0};
      if (k2 < 16) v = *(const uint4*)(BBF + BOFF_G0 + (size_t)k2 * 256 + nh * 128 + p * 64 + c);
      const unsigned short* vs = (const unsigned short*)&v;
      #pragma unroll
      for (int e = 0; e < 8; ++e) Bst[(p * 64 + c + e) * 40 + k2] = vs[e];
    }
    __syncthreads();
    #pragma unroll
    for (int nt = 0; nt < 8; ++nt){
      short8 bf = *(const short8*)&Bst[(16 * nt + r) * 40 + q * 8];
      acc0[nh * 8 + nt] = __builtin_amdgcn_mfma_f32_16x16x32_bf16(xa0, bf, acc0[nh * 8 + nt], 0, 0, 0);
      acc1[nh * 8 + nt] = __builtin_amdgcn_mfma_f32_16x16x32_bf16(xa1, bf, acc1[nh * 8 + nt], 0, 0, 0);
    }
  }
  __syncthreads();
  #pragma unroll
  for (int nt = 0; nt < 16; ++nt)
    #pragma unroll
    for (int i = 0; i < 4; ++i){
      HAs[(16 * w       + q * 4 + i) * 264 + 16 * nt + r] = f2b(acc0[nt][i]);
      HAs[(16 * (w + 4) + q * 4 + i) * 264 + 16 * nt + r] = f2b(acc1[nt][i]);
    }
  __syncthreads();

  auto attn256 = [&](int asoff, int adoff){
    float4 as4 = *(const float4*)(Wbuf + asoff + 4 * lane);
    float4 ad4 = *(const float4*)(Wbuf + adoff + 4 * lane);
    for (int it = 0; it < 32; ++it){
      int n = it * 4 + w;
      const unsigned short* hp = &HAs[n * 264 + 4 * lane];
      float e0 = b2f(hp[0]), e1 = b2f(hp[1]), e2 = b2f(hp[2]), e3 = b2f(hp[3]);
      float vs = e0 * as4.x + e1 * as4.y + e2 * as4.z + e3 * as4.w;
      float vd = e0 * ad4.x + e1 * ad4.y + e2 * ad4.z + e3 * ad4.w;
      #pragma unroll
      for (int m = 8; m >= 1; m >>= 1){ vs += __shfl_xor(vs, m); vd += __shfl_xor(vd, m); }
      if ((lane & 15) == 0){ ALSs[n * 4 + (lane >> 4)] = vs; ALDs[n * 4 + (lane >> 4)] = vd; }
    }
    __syncthreads();
    for (int pass = 0; pass < 2; ++pass){
      int jid = pass * 256 + tid;
      int n = jid >> 2, h = jid & 3;
      float aldv = ALDs[n * 4 + h];
      int rs = rowL[n], re = rowL[n + 1];
      float mx = -3e38f, den = 0.f;
      for (int j = rs; j < re; ++j){
        float v = ALSs[srcL[j] * 4 + h] + aldv;
        v = v > 0.f ? v : 0.2f * v;
        if (v > mx){ den = den * __expf(mx - v) + 1.f; mx = v; }
        else den += __expf(v - mx);
      }
      float iden = 1.f / (den + 1e-16f);
      for (int j = rs; j < re; ++j){
        float v = ALSs[srcL[j] * 4 + h] + aldv;
        v = v > 0.f ? v : 0.2f * v;
        union { _Float16 hh; unsigned short s; } uu;
        uu.hh = (_Float16)(__expf(v - mx) * iden);
        AWs[j * 4 + h] = uu.s;
      }
    }
    __syncthreads();
  };
  auto agg256 = [&](int boff){
    int f4 = (lane) * 4;
    int h = lane >> 4;
    float4 bz = *(const float4*)(Wbuf + boff + f4);
    for (int n = w; n < 128; n += 4){
      int rs = rowL[n], re = rowL[n + 1];
      float A0 = 0, A1 = 0, A2 = 0, A3 = 0;
      for (int j = rs; j < re; ++j){
        union { _Float16 hh; unsigned short s; } uu; uu.s = AWs[j * 4 + h];
        float wv = (float)uu.hh;
        const unsigned short* hp = &HAs[srcL[j] * 264 + f4];
        A0 += wv * b2f(hp[0]); A1 += wv * b2f(hp[1]);
        A2 += wv * b2f(hp[2]); A3 += wv * b2f(hp[3]);
      }
      A0 += bz.x; A1 += bz.y; A2 += bz.z; A3 += bz.w;
      unsigned short o0 = f2b(A0 > 0.f ? A0 : 0.f);
      unsigned short o1 = f2b(A1 > 0.f ? A1 : 0.f);
      unsigned short o2 = f2b(A2 > 0.f ? A2 : 0.f);
      unsigned short o3 = f2b(A3 > 0.f ? A3 : 0.f);
      uint2 pk; pk.x = (unsigned int)o0 | ((unsigned int)o1 << 16);
      pk.y = (unsigned int)o2 | ((unsigned int)o3 << 16);
      *(uint2*)&HBs[n * 264 + f4] = pk;
    }
    __syncthreads();
  };

  attn256(WOFF_G0AS, WOFF_G0AD);
  agg256(WOFF_G0B);

  //======== Layer 1 GEMM ========
  #pragma unroll
  for (int i = 0; i < 16; ++i){ acc0[i] = (float4v){0,0,0,0}; acc1[i] = (float4v){0,0,0,0}; }
  for (int kc = 0; kc < 256; kc += 32){
    short8 a0 = *(const short8*)&HBs[(16 * w       + r) * 264 + kc + q * 8];
    short8 a1 = *(const short8*)&HBs[(16 * (w + 4) + r) * 264 + kc + q * 8];
    for (int nh = 0; nh < 2; ++nh){
      __syncthreads();
      #pragma unroll
      for (int p = 0; p < 2; ++p){
        int k2 = tid >> 3, c = (tid & 7) * 8;
        uint4 v = *(const uint4*)(BBF + BOFF_G1 + (size_t)(kc + k2) * 256 + nh * 128 + p * 64 + c);
        const unsigned short* vs = (const unsigned short*)&v;
        #pragma unroll
        for (int e = 0; e < 8; ++e) Bst[(p * 64 + c + e) * 40 + k2] = vs[e];
      }
      __syncthreads();
      #pragma unroll
      for (int nt = 0; nt < 8; ++nt){
        short8 bf = *(const short8*)&Bst[(16 * nt + r) * 40 + q * 8];
        acc0[nh * 8 + nt] = __builtin_amdgcn_mfma_f32_16x16x32_bf16(a0, bf, acc0[nh * 8 + nt], 0, 0, 0);
        acc1[nh * 8 + nt] = __builtin_amdgcn_mfma_f32_16x16x32_bf16(a1, bf, acc1[nh * 8 + nt], 0, 0, 0);
      }
    }
  }
  __syncthreads();
  #pragma unroll
  for (int nt = 0; nt < 16; ++nt)
    #pragma unroll
    for (int i = 0; i < 4; ++i){
      HAs[(16 * w       + q * 4 + i) * 264 + 16 * nt + r] = f2b(acc0[nt][i]);
      HAs[(16 * (w + 4) + q * 4 + i) * 264 + 16 * nt + r] = f2b(acc1[nt][i]);
    }
  __syncthreads();

  attn256(WOFF_G1AS, WOFF_G1AD);
  agg256(WOFF_G1B);

  //======== Layer 2 GEMM ========
  #pragma unroll
  for (int i = 0; i < 4; ++i){ acc0[i] = (float4v){0,0,0,0}; acc1[i] = (float4v){0,0,0,0}; }
  for (int kc = 0; kc < 256; kc += 32){
    short8 a0 = *(const short8*)&HBs[(16 * w       + r) * 264 + kc + q * 8];
    short8 a1 = *(const short8*)&HBs[(16 * (w + 4) + r) * 264 + kc + q * 8];
    __syncthreads();
    {
      int k2 = tid >> 3, c = (tid & 7) * 8;
      uint4 v = *(const uint4*)(BBF + BOFF_G2 + (size_t)(kc + k2) * 64 + c);
      const unsigned short* vs = (const unsigned short*)&v;
      #pragma unroll
      for (int e = 0; e < 8; ++e) Bst[(c + e) * 40 + k2] = vs[e];
    }
    __syncthreads();
    #pragma unroll
    for (int nt = 0; nt < 4; ++nt){
      short8 bf = *(const short8*)&Bst[(16 * nt + r) * 40 + q * 8];
      acc0[nt] = __builtin_amdgcn_mfma_f32_16x16x32_bf16(a0, bf, acc0[nt], 0, 0, 0);
      acc1[nt] = __builtin_amdgcn_mfma_f32_16x16x32_bf16(a1, bf, acc1[nt], 0, 0, 0);
    }
  }
  __syncthreads();
  #pragma unroll
  for (int nt = 0; nt < 4; ++nt)
    #pragma unroll
    for (int i = 0; i < 4; ++i){
      HAs[(16 * w       + q * 4 + i) * 264 + 16 * nt + r] = f2b(acc0[nt][i]);
      HAs[(16 * (w + 4) + q * 4 + i) * 264 + 16 * nt + r] = f2b(acc1[nt][i]);
    }
  __syncthreads();

  //======== Layer 2 attention + agg + pool ========
  {
    float asv = Wbuf[WOFF_G2AS + lane];
    float adv = Wbuf[WOFF_G2AD + lane];
    for (int it = 0; it < 32; ++it){
      int n = it * 4 + w;
      float e0 = b2f(HAs[n * 264 + lane]);
      float vs = e0 * asv, vd = e0 * adv;
      #pragma unroll
      for (int m = 32; m >= 1; m >>= 1){ vs += __shfl_xor(vs, m); vd += __shfl_xor(vd, m); }
      if (lane == 0){ ALSs[n] = vs; ALDs[n] = vd; }
    }
    __syncthreads();
    if (tid < 128){
      int n = tid;
      float aldv = ALDs[n];
      int rs = rowL[n], re = rowL[n + 1];
      float mx = -3e38f, den = 0.f;
      for (int j = rs; j < re; ++j){
        float v = ALSs[srcL[j]] + aldv;
        v = v > 0.f ? v : 0.2f * v;
        if (v > mx){ den = den * __expf(mx - v) + 1.f; mx = v; }
        else den += __expf(v - mx);
      }
      float iden = 1.f / (den + 1e-16f);
      for (int j = rs; j < re; ++j){
        float v = ALSs[srcL[j]] + aldv;
        v = v > 0.f ? v : 0.2f * v;
        union { _Float16 hh; unsigned short s; } uu;
        uu.hh = (_Float16)(__expf(v - mx) * iden);
        AWs[j] = uu.s;
      }
    }
    __syncthreads();
    {
      int d = lane;
      float bz = Wbuf[WOFF_G2B + d];
      for (int n = w; n < 128; n += 4){
        int rs = rowL[n], re = rowL[n + 1];
        float A0 = 0.f;
        for (int j = rs; j < re; ++j){
          union { _Float16 hh; unsigned short s; } uu; uu.s = AWs[j];
          A0 += (float)uu.hh * b2f(HAs[srcL[j] * 264 + d]);
        }
        A0 += bz;
        HBs[n * 264 + d] = f2b(A0 > 0.f ? A0 : 0.f);
      }
    }
    __syncthreads();
    {
      int f = lane, part = w;
      float s = 0.f;
      for (int n = part * 32; n < part * 32 + 32; ++n) s += b2f(HBs[n * 264 + f]);
      ALSs[part * 64 + f] = s;
    }
    __syncthreads();
    if (tid < 64){
      float s = ALSs[tid] + ALSs[64 + tid] + ALSs[128 + tid] + ALSs[192 + tid];
      int b = g >> 6, tq = g & 63;
      XSEQ[(size_t)(tq * BSZ + b) * HIDD + tid] = f2b(s);
    }
  }
}

// ---------------- MFMA matmul for BOTH Wih GEMMs in one launch (z = dir) ----------------
__global__ __launch_bounds__(256)
void mmx2_kernel(const unsigned short* __restrict__ A,
                 const unsigned short* __restrict__ B0, const unsigned short* __restrict__ B1,
                 float* __restrict__ C0, float* __restrict__ C1, int M, int Nc, int K)
{
  __shared__ unsigned short As[64][40];
  __shared__ unsigned short Bs[64][40];
  const unsigned short* Bb = blockIdx.z ? B1 : B0;
  float* C = blockIdx.z ? C1 : C0;
  const int tid = threadIdx.x;
  const int w = tid >> 6, lane = tid & 63, q = lane >> 4, r = lane & 15;
  const int m0 = blockIdx.x * 64, n0 = blockIdx.y * 64;
  float4v acc0 = {0,0,0,0}, acc1 = {0,0,0,0}, acc2 = {0,0,0,0}, acc3 = {0,0,0,0};
  const int arow = tid >> 2, akb = (tid & 3) * 8;
  const int bk = tid >> 3, bnb = (tid & 7) * 8;
  for (int kc = 0; kc < K; kc += 32){
    int kw = K - kc; if (kw > 32) kw = 32;
    if (akb < kw){
      uint4 v = *(const uint4*)(A + (size_t)(m0 + arow) * K + kc + akb);
      *(uint4*)&As[arow][akb] = v;
    } else {
      uint4 z = {0,0,0,0}; *(uint4*)&As[arow][akb] = z;
    }
    if (bk < kw){
      uint4 v = *(const uint4*)(Bb + (size_t)(kc + bk) * Nc + n0 + bnb);
      const unsigned short* vs = (const unsigned short*)&v;
      #pragma unroll
      for (int e = 0; e < 8; ++e) Bs[bnb + e][bk] = vs[e];
    } else {
      #pragma unroll
      for (int e = 0; e < 8; ++e) Bs[bnb + e][bk] = 0;
    }
    __syncthreads();
    short8 af = *(const short8*)&As[16 * w + r][q * 8];
    short8 b0 = *(const short8*)&Bs[r][q * 8];
    short8 b1 = *(const short8*)&Bs[16 + r][q * 8];
    short8 b2 = *(const short8*)&Bs[32 + r][q * 8];
    short8 b3 = *(const short8*)&Bs[48 + r][q * 8];
    acc0 = __builtin_amdgcn_mfma_f32_16x16x32_bf16(af, b0, acc0, 0, 0, 0);
    acc1 = __builtin_amdgcn_mfma_f32_16x16x32_bf16(af, b1, acc1, 0, 0, 0);
    acc2 = __builtin_amdgcn_mfma_f32_16x16x32_bf16(af, b2, acc2, 0, 0, 0);
    acc3 = __builtin_amdgcn_mfma_f32_16x16x32_bf16(af, b3, acc3, 0, 0, 0);
    __syncthreads();
  }
  const int row = m0 + 16 * w + q * 4, col0 = n0 + r;
  #pragma unroll
  for (int i = 0; i < 4; ++i){
    size_t base = (size_t)(row + i) * Nc;
    C[base + col0]      = acc0[i];
    C[base + col0 + 16] = acc1[i];
    C[base + col0 + 32] = acc2[i];
    C[base + col0 + 48] = acc3[i];
  }
}

// ---------------- LSTM: 1 WG/dir, weights CU-resident (LDS + VGPR), zero sync ----------------
// 32 slabs of 16 KB: slabs 0..7 in LDS (128 KB), 8..23 pinned in VGPRs (64 regs),
// 24..31 streamed from L2 with step-start prefetch (128 KB/step).
__global__ __launch_bounds__(1024)
void lstm9_kernel(const float* __restrict__ XF, const float* __restrict__ XB,
                  const unsigned int* __restrict__ WT,
                  const float* __restrict__ bih_f, const float* __restrict__ bhh_f,
                  const float* __restrict__ bih_b, const float* __restrict__ bhh_b,
                  float* __restrict__ HT)
{
  __shared__ unsigned int WL[8][1024][4];   // 128 KB: slabs 0..7
  __shared__ unsigned int h2u[512];         // [b][128] f16 pairs
  __shared__ float glds[4][1024];           // [batch][gate-row]

  const int u = threadIdx.x;                // gate row 0..1023
  const int dir = blockIdx.x;
  const float* Xp = dir ? XB : XF;
  const uint4* WT4 = (const uint4*)(WT + (dir << 17));
  const float bias = (dir ? bih_b : bih_f)[u] + (dir ? bhh_b : bhh_f)[u];
  const int b = u >> 8, j = u & 255;        // updater mapping

  #pragma unroll
  for (int s = 0; s < 8; ++s)
    *(uint4*)WL[s][u] = WT4[(s << 10) + u];
  uint4 wv[16];                             // slabs 8..23 pinned in VGPRs
  #pragma unroll
  for (int s = 0; s < 16; ++s)
    wv[s] = WT4[((8 + s) << 10) + u];
  if (u < 512) h2u[u] = 0;
  float c = 0.f;
  __syncthreads();

  float a0, a1, a2, a3;
  auto consume = [&](int s, uint4 w4){
    uint4 hb0 = *(const uint4*)&h2u[0 * 128 + (s << 2)];
    uint4 hb1 = *(const uint4*)&h2u[1 * 128 + (s << 2)];
    uint4 hb2 = *(const uint4*)&h2u[2 * 128 + (s << 2)];
    uint4 hb3 = *(const uint4*)&h2u[3 * 128 + (s << 2)];
    a0 = dot2h(w4.x, hb0.x, a0); a0 = dot2h(w4.y, hb0.y, a0);
    a0 = dot2h(w4.z, hb0.z, a0); a0 = dot2h(w4.w, hb0.w, a0);
    a1 = dot2h(w4.x, hb1.x, a1); a1 = dot2h(w4.y, hb1.y, a1);
    a1 = dot2h(w4.z, hb1.z, a1); a1 = dot2h(w4.w, hb1.w, a1);
    a2 = dot2h(w4.x, hb2.x, a2); a2 = dot2h(w4.y, hb2.y, a2);
    a2 = dot2h(w4.z, hb2.z, a2); a2 = dot2h(w4.w, hb2.w, a2);
    a3 = dot2h(w4.x, hb3.x, a3); a3 = dot2h(w4.y, hb3.y, a3);
    a3 = dot2h(w4.z, hb3.z, a3); a3 = dot2h(w4.w, hb3.w, a3);
  };

  for (int t = 0; t < TT; ++t){
    const int tb = dir ? (TT - 1 - t) : t;
    const float* xr = Xp + (size_t)(tb * 4) * 1024 + u;
    // prefetch streamed slabs 24..31 (consumed at the end of the dot pass)
    uint4 p0 = WT4[(24 << 10) + u], p1 = WT4[(25 << 10) + u];
    uint4 p2 = WT4[(26 << 10) + u], p3 = WT4[(27 << 10) + u];
    uint4 p4 = WT4[(28 << 10) + u], p5 = WT4[(29 << 10) + u];
    uint4 p6 = WT4[(30 << 10) + u], p7 = WT4[(31 << 10) + u];
    a0 = bias + xr[0];
    a1 = bias + xr[1024];
    a2 = bias + xr[2048];
    a3 = bias + xr[3072];
    #pragma unroll
    for (int s = 0; s < 8; ++s)
      consume(s, *(const uint4*)WL[s][u]);
    #pragma unroll
    for (int s = 0; s < 16; ++s)
      consume(8 + s, wv[s]);
    consume(24, p0); consume(25, p1); consume(26, p2); consume(27, p3);
    consume(28, p4); consume(29, p5); consume(30, p6); consume(31, p7);
    glds[0][u] = a0; glds[1][u] = a1; glds[2][u] = a2; glds[3][u] = a3;
    __syncthreads();
    {
      float gi = glds[b][j];
      float gf = glds[b][256 + j];
      float gg = glds[b][512 + j];
      float go = glds[b][768 + j];
      float si = 1.f / (1.f + __expf(-gi));
      float sf = 1.f / (1.f + __expf(-gf));
      float so = 1.f / (1.f + __expf(-go));
      float tg = 1.f - 2.f / (1.f + __expf(2.f * gg));
      c = sf * c + si * tg;
      float ch = 1.f - 2.f / (1.f + __expf(2.f * c));
      float hval = so * ch;
      if (t == TT - 1){
        HT[(size_t)(dir * 4 + b) * RHID + j] = hval;
      } else {
        union { _Float16 h; unsigned short s; } uh; uh.h = (_Float16)hval;
        unsigned int own = uh.s;
        unsigned int partner = ((unsigned int)__shfl_xor((int)own, 1)) & 0xffffu;
        if ((j & 1) == 0) h2u[b * 128 + (j >> 1)] = own | (partner << 16);
      }
    }
    __syncthreads();
  }
}

// ---------------- heads + Poincare projection, fp32 out ----------------
__global__ __launch_bounds__(512)
void head2_kernel(const float* __restrict__ HT,
                  const float* __restrict__ muW, const float* __restrict__ mub,
                  const float* __restrict__ lvW, const float* __restrict__ lvb,
                  float* __restrict__ out)
{
  __shared__ float feat[4][512];
  __shared__ float muv[4][64];
  __shared__ float lvv[4][64];
  int tid = threadIdx.x;
  for (int i = tid; i < 2048; i += 512){
    int rr = i >> 8, k = i & 255;
    int b = rr & 3, d = rr >> 2;
    feat[b][d * 256 + k] = HT[i];
  }
  __syncthreads();
  int w = tid >> 6, lane = tid & 63;
  for (int job = w; job < 512; job += 8){
    int j = job & 63, b = (job >> 6) & 3, mat = job >> 8;
    const float* W = (mat ? lvW : muW) + (size_t)j * 512;
    float s = 0.f;
    #pragma unroll
    for (int e = 0; e < 8; ++e) s += W[lane * 8 + e] * feat[b][lane * 8 + e];
    #pragma unroll
    for (int mm = 32; mm >= 1; mm >>= 1) s += __shfl_xor(s, mm);
    if (lane == 0){
      float v = s + (mat ? lvb[j] : mub[j]);
      if (mat) lvv[b][j] = v; else muv[b][j] = v;
    }
  }
  __syncthreads();
  if (tid < 256){
    int b = tid >> 6, j = tid & 63;
    float mu = muv[b][j];
    float sq = mu * mu;
    #pragma unroll
    for (int mm = 32; mm >= 1; mm >>= 1) sq += __shfl_xor(sq, mm);
    float nrm = sqrtf(sq);
    const float mxn = 1.0f - 4e-3f;
    if (nrm > mxn) mu = mu / nrm * mxn;
    out[b * 64 + j] = mu;
    out[256 + b * 64 + j] = lvv[b][j];
  }
}

extern "C" void kernel_launch(void* const* d_in, const int* in_sizes, int n_in,
                              void* d_out, int out_size, void* d_ws, size_t ws_size,
                              hipStream_t stream)
{
  const int* ei = (const int*)d_in[1];

  int*   ws_i    = (int*)d_ws;
  int*   dflag   = ws_i;
  int*   csr_row = ws_i + 256;
  int*   csr_src = ws_i + 512;
  int*   csr_dst = ws_i + 2048;
  float* FW   = (float*)d_ws;
  float* Wbuf = FW + FOFF_WBUF;
  float* XFp  = FW + FOFF_XFP;
  float* XBp  = FW + FOFF_XBP;
  float* HT   = FW + FOFF_HT;
  unsigned short* XSEQ = (unsigned short*)(FW + FOFF_XSEQ);
  unsigned short* Pb   = (unsigned short*)(FW + FOFF_P);
  unsigned int*   WT   = (unsigned int*)(FW + FOFF_WE);
  unsigned short* BBF  = (unsigned short*)(FW + FOFF_BBF);

  // ---- dtype sniff + fused setup ----
  sniff_kernel<<<1, 256, 0, stream>>>((const unsigned short*)d_in[2], dflag);

  CvtArgs ca;
  static const int wsz[24] = {4096,256,256,256, 65536,256,256,256, 16384,64,64,64,
                              65536,262144,1024,1024, 65536,262144,1024,1024,
                              32768,64,32768,64};
  {
    int acc = 0;
    for (int k = 0; k < 24; ++k){ ca.src[k] = d_in[2 + k]; ca.off[k] = acc; acc += wsz[k]; }
    ca.off[24] = acc;
  }
  setup_kernel<<<(SP_TOTAL + 255) / 256, 256, 0, stream>>>(ca, dflag, Wbuf, BBF, Pb, WT, d_in[0]);
  csr_kernel<<<1, 256, 0, stream>>>(ei, csr_row, csr_src, csr_dst);

  // ---- fused GAT x3 + pool ----
  gatall_kernel<<<NGRAPH, 256, 0, stream>>>(Pb, BBF, Wbuf, csr_row, csr_src, XSEQ);

  // ---- LSTM input precompute: both directions in one launch ----
  mmx2_kernel<<<dim3(4, 16, 2), 256, 0, stream>>>(XSEQ, BBF + BOFF_WF, BBF + BOFF_WB,
                                                  XFp, XBp, 256, 1024, 64);

  // ---- LSTM: 2 WGs, CU-resident weights, zero cross-WG sync ----
  lstm9_kernel<<<2, 1024, 0, stream>>>(XFp, XBp, WT,
                                       Wbuf + WOFF_BIHF, Wbuf + WOFF_BHHF,
                                       Wbuf + WOFF_BIHB, Wbuf + WOFF_BHHB, HT);

  // ---- heads + projection ----
  head2_kernel<<<1, 512, 0, stream>>>(HT, Wbuf + WOFF_MUW, Wbuf + WOFF_MUB,
                                      Wbuf + WOFF_LVW, Wbuf + WOFF_LVB, (float*)d_out);
}

// Round 13
// 519.443 us; speedup vs baseline: 1.5050x; 1.5050x over previous
//
#include <hip/hip_runtime.h>
#include <hip/hip_bf16.h>

// ---- problem constants ----
#define BSZ 4
#define TT 64
#define NNODE 128
#define NFEAT 16
#define HIDD 64
#define NHEAD 4
#define RHID 256
#define LDIM 64
#define EPG 1024
#define NGRAPH (BSZ*TT)          // 256
#define NTOT (NGRAPH*NNODE)      // 32768
#define ESLOTS (EPG+NNODE)       // 1152

// ---- canonical fp32 weight buffer offsets (floats) ----
#define WOFF_G0W 0
#define WOFF_G0AS 4096
#define WOFF_G0AD 4352
#define WOFF_G0B 4608
#define WOFF_G1W 4864
#define WOFF_G1AS 70400
#define WOFF_G1AD 70656
#define WOFF_G1B 70912
#define WOFF_G2W 71168
#define WOFF_G2AS 87552
#define WOFF_G2AD 87616
#define WOFF_G2B 87680
#define WOFF_WIHF 87744
#define WOFF_WHHF 153280
#define WOFF_BIHF 415424
#define WOFF_BHHF 416448
#define WOFF_WIHB 417472
#define WOFF_WHHB 483008
#define WOFF_BIHB 745152
#define WOFF_BHHB 746176
#define WOFF_MUW 747200
#define WOFF_MUB 779968
#define WOFF_LVW 780032
#define WOFF_LVB 812800
#define WTOTAL   812864

// ---- workspace float offsets ----
#define FOFF_WBUF 4096
#define FOFF_SYNC 1314816      // HX: 2 dirs x 3 slots x 4 consumers x 512 uints
#define FOFF_WE   1576960      // WT (f16-pair Whh, 262144 uints)
#define FOFF_BBF  1900000      // bf16 B matrices (u16 view)
#define FOFF_XFP  2756608
#define FOFF_XBP  3018752
#define FOFF_HT   3280896
#define FOFF_XSEQ 3282944
#define FOFF_P    7485440

// bf16 B-matrix u16 offsets inside BBF
#define BOFF_G0 0
#define BOFF_G1 4096
#define BOFF_G2 69632
#define BOFF_WF 86016
#define BOFF_WB 151552
#define BTOTAL  217088

// setup phases
#define SP_CVTX  (WTOTAL + BTOTAL)            // 1029952
#define SP_WHH   (SP_CVTX + NTOT*NFEAT)       // 1554240
#define SP_TOTAL (SP_WHH + 262144)            // 1816384

#define SENT 0xFFFFFFFFu

typedef __attribute__((ext_vector_type(8))) short short8;
typedef __attribute__((ext_vector_type(4))) float float4v;

__device__ __forceinline__ float b2f(unsigned short u){
  union { unsigned int i; float f; } v; v.i = ((unsigned int)u) << 16; return v.f;
}
__device__ __forceinline__ unsigned short f2b(float f){
  __hip_bfloat16 h = __float2bfloat16(f);
  union { __hip_bfloat16 h; unsigned short u; } v; v.h = h; return v.u;
}
__device__ __forceinline__ float ldf(const void* p, int i, int flag){
  return flag ? b2f(((const unsigned short*)p)[i]) : ((const float*)p)[i];
}

// fused half2 dot: acc += w.x*h.x + w.y*h.y
__device__ __forceinline__ float dot2h(unsigned int w, unsigned int h, float acc){
#if __has_builtin(__builtin_amdgcn_fdot2)
  typedef _Float16 h2v __attribute__((ext_vector_type(2)));
  union { unsigned int u; h2v v; } a, b; a.u = w; b.u = h;
  return __builtin_amdgcn_fdot2(a.v, b.v, acc, false);
#else
  union { unsigned int u; _Float16 h[2]; } a, b; a.u = w; b.u = h;
  return acc + (float)a.h[0] * (float)b.h[0] + (float)a.h[1] * (float)b.h[1];
#endif
}

// ---------------- dtype sniff ----------------
__global__ void sniff_kernel(const unsigned short* __restrict__ w, int* __restrict__ flag){
  __shared__ int cnt;
  if (threadIdx.x == 0) cnt = 0;
  __syncthreads();
  int ok = 0;
  for (int i = threadIdx.x; i < 2048; i += 256){
    float a = fabsf(b2f(w[2 * i]));
    if (a > 1e-8f && a < 4.f) ok++;
  }
  atomicAdd(&cnt, ok);
  __syncthreads();
  if (threadIdx.x == 0) *flag = (cnt >= 1024) ? 1 : 0;
}

// ---------------- fused setup: cvtw + packb + cvtx + packwhh ----------------
struct CvtArgs {
  const void* src[24];
  int off[25];
};
__global__ void setup_kernel(CvtArgs a, const int* __restrict__ flag,
                             float* __restrict__ W, unsigned short* __restrict__ BBF,
                             unsigned short* __restrict__ P, unsigned int* __restrict__ WT,
                             const void* __restrict__ x)
{
  int id = blockIdx.x * blockDim.x + threadIdx.x;
  if (id >= SP_TOTAL) return;
  int fl = *flag;
  if (id < WTOTAL){
    int k = 0;
    while (id >= a.off[k + 1]) ++k;
    W[id] = ldf(a.src[k], id - a.off[k], fl);
  } else if (id < WTOTAL + BTOTAL){
    int r = id - WTOTAL;
    float v;
    if (r < BOFF_G1)       v = ldf(a.src[0], r, fl);
    else if (r < BOFF_G2)  v = ldf(a.src[4], r - BOFF_G1, fl);
    else if (r < BOFF_WF)  v = ldf(a.src[8], r - BOFF_G2, fl);
    else if (r < BOFF_WB){ int q = r - BOFF_WF; int k = q >> 10, n = q & 1023;
                           v = ldf(a.src[12], n * 64 + k, fl); }
    else                 { int q = r - BOFF_WB; int k = q >> 10, n = q & 1023;
                           v = ldf(a.src[16], n * 64 + k, fl); }
    BBF[r] = f2b(v);
  } else if (id < SP_CVTX + NTOT * NFEAT){
    int r = id - SP_CVTX;
    P[r] = fl ? ((const unsigned short*)x)[r] : f2b(((const float*)x)[r]);
  } else {
    int r0 = id - SP_WHH;                 // < 262144
    int d = r0 >> 17;
    int r = r0 & 131071;
    int c = r & 3;
    int u = (r >> 2) & 1023;
    int kk4 = r >> 12;
    int kk = kk4 * 4 + c;
    const void* Wsrc = d ? a.src[17] : a.src[13];   // Whh_b / Whh_f raw
    _Float16 va = (_Float16)ldf(Wsrc, u * RHID + 2 * kk, fl);
    _Float16 vb = (_Float16)ldf(Wsrc, u * RHID + 2 * kk + 1, fl);
    union { _Float16 h; unsigned short s; } ua, ub; ua.h = va; ub.h = vb;
    WT[r0] = (unsigned int)ua.s | ((unsigned int)ub.s << 16);
  }
}

// ---------------- fused 3-layer GAT + pool (+ local CSR build): one block per graph ----------------
__global__ __launch_bounds__(256, 1)
void gatall_kernel(const unsigned short* __restrict__ X,
                   const unsigned short* __restrict__ BBF,
                   const float* __restrict__ Wbuf,
                   const int* __restrict__ ei,
                   unsigned short* __restrict__ XSEQ)
{
  __shared__ unsigned short HAs[128 * 264];
  __shared__ unsigned short HBs[128 * 264];
  __shared__ unsigned short Bst[128 * 40];
  __shared__ unsigned short AWs[1152 * 4];
  __shared__ float ALSs[512];
  __shared__ float ALDs[512];
  __shared__ int   rowL[132];
  __shared__ unsigned short srcL[1152];

  const int tid = threadIdx.x;
  const int g = blockIdx.x;
  const int w = tid >> 6, lane = tid & 63, q = lane >> 4, r = lane & 15;

  // ---- local CSR build (reuse ALSs/ALDs as int scratch) ----
  {
    int* cnt = (int*)ALSs;
    int* off = (int*)ALDs;
    for (int i = tid; i < NNODE; i += 256) cnt[i] = 0;
    __syncthreads();
    for (int i = tid; i < ESLOTS; i += 256){
      int d = (i < EPG) ? ei[EPG + i] : (i - EPG);
      atomicAdd(&cnt[d], 1);
    }
    __syncthreads();
    if (tid == 0){
      int acc = 0;
      for (int i = 0; i < NNODE; ++i){ rowL[i] = acc; off[i] = acc; acc += cnt[i]; }
      rowL[NNODE] = acc;
    }
    __syncthreads();
    for (int i = tid; i < ESLOTS; i += 256){
      int s, d;
      if (i < EPG){ s = ei[i]; d = ei[EPG + i]; } else { s = i - EPG; d = i - EPG; }
      int pos = atomicAdd(&off[d], 1);
      srcL[pos] = (unsigned short)s;
    }
    __syncthreads();
  }

  float4v acc0[16], acc1[16];

  //======== Layer 0 GEMM ========
  #pragma unroll
  for (int i = 0; i < 16; ++i){ acc0[i] = (float4v){0,0,0,0}; acc1[i] = (float4v){0,0,0,0}; }
  short8 xa0 = {0,0,0,0,0,0,0,0}, xa1 = {0,0,0,0,0,0,0,0};
  if (q < 2){
    xa0 = *(const short8*)(X + ((size_t)(g * 128 + 16 * w       + r)) * 16 + q * 8);
    xa1 = *(const short8*)(X + ((size_t)(g * 128 + 16 * (w + 4) + r)) * 16 + q * 8);
  }
  for (int nh = 0; nh < 2; ++nh){
    __syncthreads();
    #pragma unroll
    for (int p = 0; p < 2; ++p){
      int k2 = tid >> 3, c = (tid & 7) * 8;
      uint4 v = {0,0,0,0};
      if (k2 < 16) v = *(const uint4*)(BBF + BOFF_G0 + (size_t)k2 * 256 + nh * 128 + p * 64 + c);
      const unsigned short* vs = (const unsigned short*)&v;
      #pragma unroll
      for (int e = 0; e < 8; ++e) Bst[(p * 64 + c + e) * 40 + k2] = vs[e];
    }
    __syncthreads();
    #pragma unroll
    for (int nt = 0; nt < 8; ++nt){
      short8 bf = *(const short8*)&Bst[(16 * nt + r) * 40 + q * 8];
      acc0[nh * 8 + nt] = __builtin_amdgcn_mfma_f32_16x16x32_bf16(xa0, bf, acc0[nh * 8 + nt], 0, 0, 0);
      acc1[nh * 8 + nt] = __builtin_amdgcn_mfma_f32_16x16x32_bf16(xa1, bf, acc1[nh * 8 + nt], 0, 0, 0);
    }
  }
  __syncthreads();
  #pragma unroll
  for (int nt = 0; nt < 16; ++nt)
    #pragma unroll
    for (int i = 0; i < 4; ++i){
      HAs[(16 * w       + q * 4 + i) * 264 + 16 * nt + r] = f2b(acc0[nt][i]);
      HAs[(16 * (w + 4) + q * 4 + i) * 264 + 16 * nt + r] = f2b(acc1[nt][i]);
    }
  __syncthreads();

  auto attn256 = [&](int asoff, int adoff){
    float4 as4 = *(const float4*)(Wbuf + asoff + 4 * lane);
    float4 ad4 = *(const float4*)(Wbuf + adoff + 4 * lane);
    for (int it = 0; it < 32; ++it){
      int n = it * 4 + w;
      const unsigned short* hp = &HAs[n * 264 + 4 * lane];
      float e0 = b2f(hp[0]), e1 = b2f(hp[1]), e2 = b2f(hp[2]), e3 = b2f(hp[3]);
      float vs = e0 * as4.x + e1 * as4.y + e2 * as4.z + e3 * as4.w;
      float vd = e0 * ad4.x + e1 * ad4.y + e2 * ad4.z + e3 * ad4.w;
      #pragma unroll
      for (int m = 8; m >= 1; m >>= 1){ vs += __shfl_xor(vs, m); vd += __shfl_xor(vd, m); }
      if ((lane & 15) == 0){ ALSs[n * 4 + (lane >> 4)] = vs; ALDs[n * 4 + (lane >> 4)] = vd; }
    }
    __syncthreads();
    for (int pass = 0; pass < 2; ++pass){
      int jid = pass * 256 + tid;
      int n = jid >> 2, h = jid & 3;
      float aldv = ALDs[n * 4 + h];
      int rs = rowL[n], re = rowL[n + 1];
      float mx = -3e38f, den = 0.f;
      for (int j = rs; j < re; ++j){
        float v = ALSs[srcL[j] * 4 + h] + aldv;
        v = v > 0.f ? v : 0.2f * v;
        if (v > mx){ den = den * __expf(mx - v) + 1.f; mx = v; }
        else den += __expf(v - mx);
      }
      float iden = 1.f / (den + 1e-16f);
      for (int j = rs; j < re; ++j){
        float v = ALSs[srcL[j] * 4 + h] + aldv;
        v = v > 0.f ? v : 0.2f * v;
        union { _Float16 hh; unsigned short s; } uu;
        uu.hh = (_Float16)(__expf(v - mx) * iden);
        AWs[j * 4 + h] = uu.s;
      }
    }
    __syncthreads();
  };
  auto agg256 = [&](int boff){
    int f4 = (lane) * 4;
    int h = lane >> 4;
    float4 bz = *(const float4*)(Wbuf + boff + f4);
    for (int n = w; n < 128; n += 4){
      int rs = rowL[n], re = rowL[n + 1];
      float A0 = 0, A1 = 0, A2 = 0, A3 = 0;
      for (int j = rs; j < re; ++j){
        union { _Float16 hh; unsigned short s; } uu; uu.s = AWs[j * 4 + h];
        float wv = (float)uu.hh;
        const unsigned short* hp = &HAs[srcL[j] * 264 + f4];
        A0 += wv * b2f(hp[0]); A1 += wv * b2f(hp[1]);
        A2 += wv * b2f(hp[2]); A3 += wv * b2f(hp[3]);
      }
      A0 += bz.x; A1 += bz.y; A2 += bz.z; A3 += bz.w;
      unsigned short o0 = f2b(A0 > 0.f ? A0 : 0.f);
      unsigned short o1 = f2b(A1 > 0.f ? A1 : 0.f);
      unsigned short o2 = f2b(A2 > 0.f ? A2 : 0.f);
      unsigned short o3 = f2b(A3 > 0.f ? A3 : 0.f);
      uint2 pk; pk.x = (unsigned int)o0 | ((unsigned int)o1 << 16);
      pk.y = (unsigned int)o2 | ((unsigned int)o3 << 16);
      *(uint2*)&HBs[n * 264 + f4] = pk;
    }
    __syncthreads();
  };

  attn256(WOFF_G0AS, WOFF_G0AD);
  agg256(WOFF_G0B);

  //======== Layer 1 GEMM ========
  #pragma unroll
  for (int i = 0; i < 16; ++i){ acc0[i] = (float4v){0,0,0,0}; acc1[i] = (float4v){0,0,0,0}; }
  for (int kc = 0; kc < 256; kc += 32){
    short8 a0 = *(const short8*)&HBs[(16 * w       + r) * 264 + kc + q * 8];
    short8 a1 = *(const short8*)&HBs[(16 * (w + 4) + r) * 264 + kc + q * 8];
    for (int nh = 0; nh < 2; ++nh){
      __syncthreads();
      #pragma unroll
      for (int p = 0; p < 2; ++p){
        int k2 = tid >> 3, c = (tid & 7) * 8;
        uint4 v = *(const uint4*)(BBF + BOFF_G1 + (size_t)(kc + k2) * 256 + nh * 128 + p * 64 + c);
        const unsigned short* vs = (const unsigned short*)&v;
        #pragma unroll
        for (int e = 0; e < 8; ++e) Bst[(p * 64 + c + e) * 40 + k2] = vs[e];
      }
      __syncthreads();
      #pragma unroll
      for (int nt = 0; nt < 8; ++nt){
        short8 bf = *(const short8*)&Bst[(16 * nt + r) * 40 + q * 8];
        acc0[nh * 8 + nt] = __builtin_amdgcn_mfma_f32_16x16x32_bf16(a0, bf, acc0[nh * 8 + nt], 0, 0, 0);
        acc1[nh * 8 + nt] = __builtin_amdgcn_mfma_f32_16x16x32_bf16(a1, bf, acc1[nh * 8 + nt], 0, 0, 0);
      }
    }
  }
  __syncthreads();
  #pragma unroll
  for (int nt = 0; nt < 16; ++nt)
    #pragma unroll
    for (int i = 0; i < 4; ++i){
      HAs[(16 * w       + q * 4 + i) * 264 + 16 * nt + r] = f2b(acc0[nt][i]);
      HAs[(16 * (w + 4) + q * 4 + i) * 264 + 16 * nt + r] = f2b(acc1[nt][i]);
    }
  __syncthreads();

  attn256(WOFF_G1AS, WOFF_G1AD);
  agg256(WOFF_G1B);

  //======== Layer 2 GEMM ========
  #pragma unroll
  for (int i = 0; i < 4; ++i){ acc0[i] = (float4v){0,0,0,0}; acc1[i] = (float4v){0,0,0,0}; }
  for (int kc = 0; kc < 256; kc += 32){
    short8 a0 = *(const short8*)&HBs[(16 * w       + r) * 264 + kc + q * 8];
    short8 a1 = *(const short8*)&HBs[(16 * (w + 4) + r) * 264 + kc + q * 8];
    __syncthreads();
    {
      int k2 = tid >> 3, c = (tid & 7) * 8;
      uint4 v = *(const uint4*)(BBF + BOFF_G2 + (size_t)(kc + k2) * 64 + c);
      const unsigned short* vs = (const unsigned short*)&v;
      #pragma unroll
      for (int e = 0; e < 8; ++e) Bst[(c + e) * 40 + k2] = vs[e];
    }
    __syncthreads();
    #pragma unroll
    for (int nt = 0; nt < 4; ++nt){
      short8 bf = *(const short8*)&Bst[(16 * nt + r) * 40 + q * 8];
      acc0[nt] = __builtin_amdgcn_mfma_f32_16x16x32_bf16(a0, bf, acc0[nt], 0, 0, 0);
      acc1[nt] = __builtin_amdgcn_mfma_f32_16x16x32_bf16(a1, bf, acc1[nt], 0, 0, 0);
    }
  }
  __syncthreads();
  #pragma unroll
  for (int nt = 0; nt < 4; ++nt)
    #pragma unroll
    for (int i = 0; i < 4; ++i){
      HAs[(16 * w       + q * 4 + i) * 264 + 16 * nt + r] = f2b(acc0[nt][i]);
      HAs[(16 * (w + 4) + q * 4 + i) * 264 + 16 * nt + r] = f2b(acc1[nt][i]);
    }
  __syncthreads();

  //======== Layer 2 attention + agg + pool ========
  {
    float asv = Wbuf[WOFF_G2AS + lane];
    float adv = Wbuf[WOFF_G2AD + lane];
    for (int it = 0; it < 32; ++it){
      int n = it * 4 + w;
      float e0 = b2f(HAs[n * 264 + lane]);
      float vs = e0 * asv, vd = e0 * adv;
      #pragma unroll
      for (int m = 32; m >= 1; m >>= 1){ vs += __shfl_xor(vs, m); vd += __shfl_xor(vd, m); }
      if (lane == 0){ ALSs[n] = vs; ALDs[n] = vd; }
    }
    __syncthreads();
    if (tid < 128){
      int n = tid;
      float aldv = ALDs[n];
      int rs = rowL[n], re = rowL[n + 1];
      float mx = -3e38f, den = 0.f;
      for (int j = rs; j < re; ++j){
        float v = ALSs[srcL[j]] + aldv;
        v = v > 0.f ? v : 0.2f * v;
        if (v > mx){ den = den * __expf(mx - v) + 1.f; mx = v; }
        else den += __expf(v - mx);
      }
      float iden = 1.f / (den + 1e-16f);
      for (int j = rs; j < re; ++j){
        float v = ALSs[srcL[j]] + aldv;
        v = v > 0.f ? v : 0.2f * v;
        union { _Float16 hh; unsigned short s; } uu;
        uu.hh = (_Float16)(__expf(v - mx) * iden);
        AWs[j] = uu.s;
      }
    }
    __syncthreads();
    {
      int d = lane;
      float bz = Wbuf[WOFF_G2B + d];
      for (int n = w; n < 128; n += 4){
        int rs = rowL[n], re = rowL[n + 1];
        float A0 = 0.f;
        for (int j = rs; j < re; ++j){
          union { _Float16 hh; unsigned short s; } uu; uu.s = AWs[j];
          A0 += (float)uu.hh * b2f(HAs[srcL[j] * 264 + d]);
        }
        A0 += bz;
        HBs[n * 264 + d] = f2b(A0 > 0.f ? A0 : 0.f);
      }
    }
    __syncthreads();
    {
      int f = lane, part = w;
      float s = 0.f;
      for (int n = part * 32; n < part * 32 + 32; ++n) s += b2f(HBs[n * 264 + f]);
      ALSs[part * 64 + f] = s;
    }
    __syncthreads();
    if (tid < 64){
      float s = ALSs[tid] + ALSs[64 + tid] + ALSs[128 + tid] + ALSs[192 + tid];
      int b = g >> 6, tq = g & 63;
      XSEQ[(size_t)(tq * BSZ + b) * HIDD + tid] = f2b(s);
    }
  }
}

// ---------------- MFMA matmul for BOTH Wih GEMMs in one launch (z = dir) ----------------
__global__ __launch_bounds__(256)
void mmx2_kernel(const unsigned short* __restrict__ A,
                 const unsigned short* __restrict__ B0, const unsigned short* __restrict__ B1,
                 float* __restrict__ C0, float* __restrict__ C1, int M, int Nc, int K)
{
  __shared__ unsigned short As[64][40];
  __shared__ unsigned short Bs[64][40];
  const unsigned short* Bb = blockIdx.z ? B1 : B0;
  float* C = blockIdx.z ? C1 : C0;
  const int tid = threadIdx.x;
  const int w = tid >> 6, lane = tid & 63, q = lane >> 4, r = lane & 15;
  const int m0 = blockIdx.x * 64, n0 = blockIdx.y * 64;
  float4v acc0 = {0,0,0,0}, acc1 = {0,0,0,0}, acc2 = {0,0,0,0}, acc3 = {0,0,0,0};
  const int arow = tid >> 2, akb = (tid & 3) * 8;
  const int bk = tid >> 3, bnb = (tid & 7) * 8;
  for (int kc = 0; kc < K; kc += 32){
    int kw = K - kc; if (kw > 32) kw = 32;
    if (akb < kw){
      uint4 v = *(const uint4*)(A + (size_t)(m0 + arow) * K + kc + akb);
      *(uint4*)&As[arow][akb] = v;
    } else {
      uint4 z = {0,0,0,0}; *(uint4*)&As[arow][akb] = z;
    }
    if (bk < kw){
      uint4 v = *(const uint4*)(Bb + (size_t)(kc + bk) * Nc + n0 + bnb);
      const unsigned short* vs = (const unsigned short*)&v;
      #pragma unroll
      for (int e = 0; e < 8; ++e) Bs[bnb + e][bk] = vs[e];
    } else {
      #pragma unroll
      for (int e = 0; e < 8; ++e) Bs[bnb + e][bk] = 0;
    }
    __syncthreads();
    short8 af = *(const short8*)&As[16 * w + r][q * 8];
    short8 b0 = *(const short8*)&Bs[r][q * 8];
    short8 b1 = *(const short8*)&Bs[16 + r][q * 8];
    short8 b2 = *(const short8*)&Bs[32 + r][q * 8];
    short8 b3 = *(const short8*)&Bs[48 + r][q * 8];
    acc0 = __builtin_amdgcn_mfma_f32_16x16x32_bf16(af, b0, acc0, 0, 0, 0);
    acc1 = __builtin_amdgcn_mfma_f32_16x16x32_bf16(af, b1, acc1, 0, 0, 0);
    acc2 = __builtin_amdgcn_mfma_f32_16x16x32_bf16(af, b2, acc2, 0, 0, 0);
    acc3 = __builtin_amdgcn_mfma_f32_16x16x32_bf16(af, b3, acc3, 0, 0, 0);
    __syncthreads();
  }
  const int row = m0 + 16 * w + q * 4, col0 = n0 + r;
  #pragma unroll
  for (int i = 0; i < 4; ++i){
    size_t base = (size_t)(row + i) * Nc;
    C[base + col0]      = acc0[i];
    C[base + col0 + 16] = acc1[i];
    C[base + col0 + 32] = acc2[i];
    C[base + col0 + 48] = acc3[i];
  }
}

// ---------------- LSTM, M-split, sentinel-payload sync with PER-CONSUMER copies ----------------
// 8 WGs = 2 dirs x 4 slices. HX[dir][slot:3][consumer:4][512], init SENT (0xFFFFFFFF =
// two f16 NaNs — unreachable by real h). Publisher writes its slice into the 3 peer
// consumers' private regions; each element has exactly ONE reader, which consumes then
// clears to SENT (one-shot restored — R12's shared-read clear caused the deadlock).
// Clear drains at reader's next __syncthreads (vmcnt(0) before s_barrier), strictly
// before its own next publish is issued; producer rewrites the slot only at t+3 after
// observing that publish — so clears are visible before slot reuse.
__global__ __launch_bounds__(256)
void lstm12_kernel(const float* __restrict__ XF, const float* __restrict__ XB,
                   const unsigned int* __restrict__ WT,
                   const float* __restrict__ bih_f, const float* __restrict__ bhh_f,
                   const float* __restrict__ bih_b, const float* __restrict__ bhh_b,
                   unsigned int* __restrict__ HX,
                   float* __restrict__ HT)
{
  __shared__ unsigned int WL[32][256][4];
  __shared__ unsigned int h2u[512];
  __shared__ float glds[4][64][5];

  const int tid = threadIdx.x;
  const int m = blockIdx.x & 3, dir = blockIdx.x >> 2;
  const int gq = tid >> 6, jl = tid & 63;
  const int u = gq * 256 + 64 * m + jl;
  const float* Xp = dir ? XB : XF;
  const float bias = (dir ? bih_b : bih_f)[u] + (dir ? bhh_b : bhh_f)[u];
  const int ub = tid >> 6, uj = tid & 63;
  unsigned int* HXd = HX + dir * 6144;       // [slot:3][consumer:4][512]

  {
    const uint4* WT4 = (const uint4*)(WT + (dir << 17));
    #pragma unroll
    for (int kk4 = 0; kk4 < 32; ++kk4)
      *(uint4*)WL[kk4][tid] = WT4[(kk4 << 10) + u];
  }
  for (int i = tid; i < 512; i += 256) h2u[i] = 0;
  float c = 0.f;
  __syncthreads();

  float a0, a1, a2, a3;
  auto consume = [&](int kk4){
    uint4 w4 = *(const uint4*)WL[kk4][tid];
    uint4 hb0 = *(const uint4*)&h2u[0 * 128 + (kk4 << 2)];
    uint4 hb1 = *(const uint4*)&h2u[1 * 128 + (kk4 << 2)];
    uint4 hb2 = *(const uint4*)&h2u[2 * 128 + (kk4 << 2)];
    uint4 hb3 = *(const uint4*)&h2u[3 * 128 + (kk4 << 2)];
    a0 = dot2h(w4.x, hb0.x, a0); a0 = dot2h(w4.y, hb0.y, a0);
    a0 = dot2h(w4.z, hb0.z, a0); a0 = dot2h(w4.w, hb0.w, a0);
    a1 = dot2h(w4.x, hb1.x, a1); a1 = dot2h(w4.y, hb1.y, a1);
    a1 = dot2h(w4.z, hb1.z, a1); a1 = dot2h(w4.w, hb1.w, a1);
    a2 = dot2h(w4.x, hb2.x, a2); a2 = dot2h(w4.y, hb2.y, a2);
    a2 = dot2h(w4.z, hb2.z, a2); a2 = dot2h(w4.w, hb2.w, a2);
    a3 = dot2h(w4.x, hb3.x, a3); a3 = dot2h(w4.y, hb3.y, a3);
    a3 = dot2h(w4.z, hb3.z, a3); a3 = dot2h(w4.w, hb3.w, a3);
  };

  for (int t = 0; t < TT; ++t){
    const int tb = dir ? (TT - 1 - t) : t;
    const float* xr = Xp + (size_t)(tb * 4) * 1024 + u;
    a0 = bias + xr[0];
    a1 = bias + xr[1024];
    a2 = bias + xr[2048];
    a3 = bias + xr[3072];
    // Phase A: own K-chunk (peer-independent — overlaps peers' publish latency)
    #pragma unroll
    for (int i = 0; i < 8; ++i) consume(8 * m + i);
    // Phase B: fetch peer slices of h(t-1) from this WG's consumer region, poll payload
    if (t > 0 && gq > 0){
      int qp = (m + gq) & 3;
      unsigned int* S = HXd + ((t - 1) % 3) * 2048 + m * 512;
      int b2 = jl >> 5, p2 = jl & 31;
      int i1 = b2 * 128 + 32 * qp + p2;
      int i2 = (b2 + 2) * 128 + 32 * qp + p2;
      unsigned int v1, v2;
      int guard = 0;
      while ((v1 = __hip_atomic_load(&S[i1], __ATOMIC_RELAXED, __HIP_MEMORY_SCOPE_AGENT)) == SENT
             && guard < 200000){ __builtin_amdgcn_s_sleep(1); ++guard; }
      guard = 0;
      while ((v2 = __hip_atomic_load(&S[i2], __ATOMIC_RELAXED, __HIP_MEMORY_SCOPE_AGENT)) == SENT
             && guard < 200000){ __builtin_amdgcn_s_sleep(1); ++guard; }
      h2u[i1] = v1; h2u[i2] = v2;
      __hip_atomic_store(&S[i1], SENT, __ATOMIC_RELAXED, __HIP_MEMORY_SCOPE_AGENT);
      __hip_atomic_store(&S[i2], SENT, __ATOMIC_RELAXED, __HIP_MEMORY_SCOPE_AGENT);
    }
    __syncthreads();
    // Phase C: peer K-chunks
    #pragma unroll
    for (int i = 1; i < 4; ++i){
      int qp = (m + i) & 3;
      #pragma unroll
      for (int s = 0; s < 8; ++s) consume(8 * qp + s);
    }
    glds[gq][jl][0] = a0; glds[gq][jl][1] = a1;
    glds[gq][jl][2] = a2; glds[gq][jl][3] = a3;
    __syncthreads();

    float gi = glds[0][uj][ub];
    float gf = glds[1][uj][ub];
    float gg = glds[2][uj][ub];
    float go = glds[3][uj][ub];
    float si = 1.f / (1.f + __expf(-gi));
    float sf = 1.f / (1.f + __expf(-gf));
    float so = 1.f / (1.f + __expf(-go));
    float tg = 1.f - 2.f / (1.f + __expf(2.f * gg));
    c = sf * c + si * tg;
    float ch = 1.f - 2.f / (1.f + __expf(2.f * c));
    float hval = so * ch;
    if (t == TT - 1){
      HT[(size_t)(dir * 4 + ub) * RHID + (64 * m + uj)] = hval;
      break;
    }
    union { _Float16 h; unsigned short s; } uh; uh.h = (_Float16)hval;
    unsigned int own = uh.s;
    unsigned int partner = ((unsigned int)__shfl_xor((int)own, 1)) & 0xffffu;
    unsigned int* S = HXd + (t % 3) * 2048;
    if ((uj & 1) == 0){
      unsigned int v = own | (partner << 16);
      int p = uj >> 1;
      int idx = ub * 128 + 32 * m + p;
      h2u[idx] = v;
      #pragma unroll
      for (int cns = 1; cns < 4; ++cns)
        __hip_atomic_store(&S[((m + cns) & 3) * 512 + idx], v,
                           __ATOMIC_RELAXED, __HIP_MEMORY_SCOPE_AGENT);
    }
    __syncthreads();   // drains publish + clears before next step
  }
}

// ---------------- heads + Poincare projection, fp32 out ----------------
__global__ __launch_bounds__(512)
void head2_kernel(const float* __restrict__ HT,
                  const float* __restrict__ muW, const float* __restrict__ mub,
                  const float* __restrict__ lvW, const float* __restrict__ lvb,
                  float* __restrict__ out)
{
  __shared__ float feat[4][512];
  __shared__ float muv[4][64];
  __shared__ float lvv[4][64];
  int tid = threadIdx.x;
  for (int i = tid; i < 2048; i += 512){
    int rr = i >> 8, k = i & 255;
    int b = rr & 3, d = rr >> 2;
    feat[b][d * 256 + k] = HT[i];
  }
  __syncthreads();
  int w = tid >> 6, lane = tid & 63;
  for (int job = w; job < 512; job += 8){
    int j = job & 63, b = (job >> 6) & 3, mat = job >> 8;
    const float* W = (mat ? lvW : muW) + (size_t)j * 512;
    float s = 0.f;
    #pragma unroll
    for (int e = 0; e < 8; ++e) s += W[lane * 8 + e] * feat[b][lane * 8 + e];
    #pragma unroll
    for (int mm = 32; mm >= 1; mm >>= 1) s += __shfl_xor(s, mm);
    if (lane == 0){
      float v = s + (mat ? lvb[j] : mub[j]);
      if (mat) lvv[b][j] = v; else muv[b][j] = v;
    }
  }
  __syncthreads();
  if (tid < 256){
    int b = tid >> 6, j = tid & 63;
    float mu = muv[b][j];
    float sq = mu * mu;
    #pragma unroll
    for (int mm = 32; mm >= 1; mm >>= 1) sq += __shfl_xor(sq, mm);
    float nrm = sqrtf(sq);
    const float mxn = 1.0f - 4e-3f;
    if (nrm > mxn) mu = mu / nrm * mxn;
    out[b * 64 + j] = mu;
    out[256 + b * 64 + j] = lvv[b][j];
  }
}

extern "C" void kernel_launch(void* const* d_in, const int* in_sizes, int n_in,
                              void* d_out, int out_size, void* d_ws, size_t ws_size,
                              hipStream_t stream)
{
  const int* ei = (const int*)d_in[1];

  int*   ws_i    = (int*)d_ws;
  int*   dflag   = ws_i;
  float* FW   = (float*)d_ws;
  float* Wbuf = FW + FOFF_WBUF;
  float* XFp  = FW + FOFF_XFP;
  float* XBp  = FW + FOFF_XBP;
  float* HT   = FW + FOFF_HT;
  unsigned short* XSEQ = (unsigned short*)(FW + FOFF_XSEQ);
  unsigned short* Pb   = (unsigned short*)(FW + FOFF_P);
  unsigned int*   WT   = (unsigned int*)(FW + FOFF_WE);
  unsigned short* BBF  = (unsigned short*)(FW + FOFF_BBF);
  unsigned int*   HX   = (unsigned int*)(FW + FOFF_SYNC);   // 2*3*4*512 uints

  // ---- dtype sniff + fused setup ----
  sniff_kernel<<<1, 256, 0, stream>>>((const unsigned short*)d_in[2], dflag);

  CvtArgs ca;
  static const int wsz[24] = {4096,256,256,256, 65536,256,256,256, 16384,64,64,64,
                              65536,262144,1024,1024, 65536,262144,1024,1024,
                              32768,64,32768,64};
  {
    int acc = 0;
    for (int k = 0; k < 24; ++k){ ca.src[k] = d_in[2 + k]; ca.off[k] = acc; acc += wsz[k]; }
    ca.off[24] = acc;
  }
  setup_kernel<<<(SP_TOTAL + 255) / 256, 256, 0, stream>>>(ca, dflag, Wbuf, BBF, Pb, WT, d_in[0]);

  // ---- fused GAT x3 + pool (CSR built per-block) ----
  gatall_kernel<<<NGRAPH, 256, 0, stream>>>(Pb, BBF, Wbuf, ei, XSEQ);

  // ---- LSTM input precompute: both directions in one launch ----
  mmx2_kernel<<<dim3(4, 16, 2), 256, 0, stream>>>(XSEQ, BBF + BOFF_WF, BBF + BOFF_WB,
                                                  XFp, XBp, 256, 1024, 64);

  // ---- LSTM: sentinel-payload protocol, per-consumer copies (HX starts as SENT) ----
  hipMemsetAsync((void*)HX, 0xFF, 2 * 3 * 4 * 512 * 4, stream);
  lstm12_kernel<<<8, 256, 0, stream>>>(XFp, XBp, WT,
                                       Wbuf + WOFF_BIHF, Wbuf + WOFF_BHHF,
                                       Wbuf + WOFF_BIHB, Wbuf + WOFF_BHHB,
                                       HX, HT);

  // ---- heads + projection ----
  head2_kernel<<<1, 512, 0, stream>>>(HT, Wbuf + WOFF_MUW, Wbuf + WOFF_MUB,
                                      Wbuf + WOFF_LVW, Wbuf + WOFF_LVB, (float*)d_out);
}

// Round 15
// 514.122 us; speedup vs baseline: 1.5206x; 1.0103x over previous
//
#include <hip/hip_runtime.h>
#include <hip/hip_bf16.h>

// ---- problem constants ----
#define BSZ 4
#define TT 64
#define NNODE 128
#define NFEAT 16
#define HIDD 64
#define NHEAD 4
#define RHID 256
#define LDIM 64
#define EPG 1024
#define NGRAPH (BSZ*TT)          // 256
#define NTOT (NGRAPH*NNODE)      // 32768
#define ESLOTS (EPG+NNODE)       // 1152

// ---- canonical fp32 weight buffer offsets (floats) ----
#define WOFF_G0W 0
#define WOFF_G0AS 4096
#define WOFF_G0AD 4352
#define WOFF_G0B 4608
#define WOFF_G1W 4864
#define WOFF_G1AS 70400
#define WOFF_G1AD 70656
#define WOFF_G1B 70912
#define WOFF_G2W 71168
#define WOFF_G2AS 87552
#define WOFF_G2AD 87616
#define WOFF_G2B 87680
#define WOFF_WIHF 87744
#define WOFF_WHHF 153280
#define WOFF_BIHF 415424
#define WOFF_BHHF 416448
#define WOFF_WIHB 417472
#define WOFF_WHHB 483008
#define WOFF_BIHB 745152
#define WOFF_BHHB 746176
#define WOFF_MUW 747200
#define WOFF_MUB 779968
#define WOFF_LVW 780032
#define WOFF_LVB 812800
#define WTOTAL   812864

// ---- workspace float offsets ----
#define FOFF_WBUF 4096
#define FOFF_SYNC 1314816      // HX: 2 dirs x 3 slots x 4 consumers x 512 uints
#define FOFF_WE   1576960      // WT (f16-pair Whh, 262144 uints)
#define FOFF_BBF  1900000      // bf16 B matrices (u16 view)
#define FOFF_XFP  2756608
#define FOFF_XBP  3018752
#define FOFF_HT   3280896
#define FOFF_XSEQ 3282944
#define FOFF_P    7485440

// bf16 B-matrix u16 offsets inside BBF
#define BOFF_G0 0
#define BOFF_G1 4096
#define BOFF_G2 69632
#define BOFF_WF 86016
#define BOFF_WB 151552
#define BTOTAL  217088

// setup phases
#define SP_CVTX  (WTOTAL + BTOTAL)            // 1029952
#define SP_WHH   (SP_CVTX + NTOT*NFEAT)       // 1554240
#define SP_TOTAL (SP_WHH + 262144)            // 1816384

#define SENT 0xFFFFFFFFu

typedef __attribute__((ext_vector_type(8))) short short8;
typedef __attribute__((ext_vector_type(4))) float float4v;

__device__ __forceinline__ float b2f(unsigned short u){
  union { unsigned int i; float f; } v; v.i = ((unsigned int)u) << 16; return v.f;
}
__device__ __forceinline__ unsigned short f2b(float f){
  __hip_bfloat16 h = __float2bfloat16(f);
  union { __hip_bfloat16 h; unsigned short u; } v; v.h = h; return v.u;
}
__device__ __forceinline__ float ldf(const void* p, int i, int flag){
  return flag ? b2f(((const unsigned short*)p)[i]) : ((const float*)p)[i];
}
__device__ __forceinline__ float h2f(unsigned short s){
  union { _Float16 hh; unsigned short s; } u; u.s = s; return (float)u.hh;
}

// fused half2 dot: acc += w.x*h.x + w.y*h.y
__device__ __forceinline__ float dot2h(unsigned int w, unsigned int h, float acc){
#if __has_builtin(__builtin_amdgcn_fdot2)
  typedef _Float16 h2v __attribute__((ext_vector_type(2)));
  union { unsigned int u; h2v v; } a, b; a.u = w; b.u = h;
  return __builtin_amdgcn_fdot2(a.v, b.v, acc, false);
#else
  union { unsigned int u; _Float16 h[2]; } a, b; a.u = w; b.u = h;
  return acc + (float)a.h[0] * (float)b.h[0] + (float)a.h[1] * (float)b.h[1];
#endif
}

// ---------------- dtype sniff ----------------
__global__ void sniff_kernel(const unsigned short* __restrict__ w, int* __restrict__ flag){
  __shared__ int cnt;
  if (threadIdx.x == 0) cnt = 0;
  __syncthreads();
  int ok = 0;
  for (int i = threadIdx.x; i < 2048; i += 256){
    float a = fabsf(b2f(w[2 * i]));
    if (a > 1e-8f && a < 4.f) ok++;
  }
  atomicAdd(&cnt, ok);
  __syncthreads();
  if (threadIdx.x == 0) *flag = (cnt >= 1024) ? 1 : 0;
}

// ---------------- fused setup: cvtw + packb + cvtx + packwhh ----------------
struct CvtArgs {
  const void* src[24];
  int off[25];
};
__global__ void setup_kernel(CvtArgs a, const int* __restrict__ flag,
                             float* __restrict__ W, unsigned short* __restrict__ BBF,
                             unsigned short* __restrict__ P, unsigned int* __restrict__ WT,
                             const void* __restrict__ x)
{
  int id = blockIdx.x * blockDim.x + threadIdx.x;
  if (id >= SP_TOTAL) return;
  int fl = *flag;
  if (id < WTOTAL){
    int k = 0;
    while (id >= a.off[k + 1]) ++k;
    W[id] = ldf(a.src[k], id - a.off[k], fl);
  } else if (id < WTOTAL + BTOTAL){
    int r = id - WTOTAL;
    float v;
    if (r < BOFF_G1)       v = ldf(a.src[0], r, fl);
    else if (r < BOFF_G2)  v = ldf(a.src[4], r - BOFF_G1, fl);
    else if (r < BOFF_WF)  v = ldf(a.src[8], r - BOFF_G2, fl);
    else if (r < BOFF_WB){ int q = r - BOFF_WF; int k = q >> 10, n = q & 1023;
                           v = ldf(a.src[12], n * 64 + k, fl); }
    else                 { int q = r - BOFF_WB; int k = q >> 10, n = q & 1023;
                           v = ldf(a.src[16], n * 64 + k, fl); }
    BBF[r] = f2b(v);
  } else if (id < SP_CVTX + NTOT * NFEAT){
    int r = id - SP_CVTX;
    P[r] = fl ? ((const unsigned short*)x)[r] : f2b(((const float*)x)[r]);
  } else {
    int r0 = id - SP_WHH;                 // < 262144
    int d = r0 >> 17;
    int r = r0 & 131071;
    int c = r & 3;
    int u = (r >> 2) & 1023;
    int kk4 = r >> 12;
    int kk = kk4 * 4 + c;
    const void* Wsrc = d ? a.src[17] : a.src[13];   // Whh_b / Whh_f raw
    _Float16 va = (_Float16)ldf(Wsrc, u * RHID + 2 * kk, fl);
    _Float16 vb = (_Float16)ldf(Wsrc, u * RHID + 2 * kk + 1, fl);
    union { _Float16 h; unsigned short s; } ua, ub; ua.h = va; ub.h = vb;
    WT[r0] = (unsigned int)ua.s | ((unsigned int)ub.s << 16);
  }
}

// ---------------- fused 3-layer GAT + pool (+ local CSR): one 256-thread block per graph ----------------
// R13 structure (known-good) + 4-way load ILP in the serial edge loops.
__global__ __launch_bounds__(256, 1)
void gatall_kernel(const unsigned short* __restrict__ X,
                   const unsigned short* __restrict__ BBF,
                   const float* __restrict__ Wbuf,
                   const int* __restrict__ ei,
                   unsigned short* __restrict__ XSEQ)
{
  __shared__ unsigned short HAs[128 * 264];
  __shared__ unsigned short HBs[128 * 264];
  __shared__ unsigned short Bst[128 * 40];
  __shared__ unsigned short AWs[1152 * 4];
  __shared__ float ALSs[512];
  __shared__ float ALDs[512];
  __shared__ int   rowL[132];
  __shared__ unsigned short srcL[1152];

  const int tid = threadIdx.x;
  const int g = blockIdx.x;
  const int w = tid >> 6, lane = tid & 63, q = lane >> 4, r = lane & 15;

  // ---- local CSR build (reuse ALSs/ALDs as int scratch) ----
  {
    int* cnt = (int*)ALSs;
    int* off = (int*)ALDs;
    for (int i = tid; i < NNODE; i += 256) cnt[i] = 0;
    __syncthreads();
    for (int i = tid; i < ESLOTS; i += 256){
      int d = (i < EPG) ? ei[EPG + i] : (i - EPG);
      atomicAdd(&cnt[d], 1);
    }
    __syncthreads();
    if (tid == 0){
      int acc = 0;
      for (int i = 0; i < NNODE; ++i){ rowL[i] = acc; off[i] = acc; acc += cnt[i]; }
      rowL[NNODE] = acc;
    }
    __syncthreads();
    for (int i = tid; i < ESLOTS; i += 256){
      int s, d;
      if (i < EPG){ s = ei[i]; d = ei[EPG + i]; } else { s = i - EPG; d = i - EPG; }
      int pos = atomicAdd(&off[d], 1);
      srcL[pos] = (unsigned short)s;
    }
    __syncthreads();
  }

  float4v acc0[16], acc1[16];

  //======== Layer 0 GEMM ========
  #pragma unroll
  for (int i = 0; i < 16; ++i){ acc0[i] = (float4v){0,0,0,0}; acc1[i] = (float4v){0,0,0,0}; }
  short8 xa0 = {0,0,0,0,0,0,0,0}, xa1 = {0,0,0,0,0,0,0,0};
  if (q < 2){
    xa0 = *(const short8*)(X + ((size_t)(g * 128 + 16 * w       + r)) * 16 + q * 8);
    xa1 = *(const short8*)(X + ((size_t)(g * 128 + 16 * (w + 4) + r)) * 16 + q * 8);
  }
  for (int nh = 0; nh < 2; ++nh){
    __syncthreads();
    #pragma unroll
    for (int p = 0; p < 2; ++p){
      int k2 = tid >> 3, c = (tid & 7) * 8;
      uint4 v = {0,0,0,0};
      if (k2 < 16) v = *(const uint4*)(BBF + BOFF_G0 + (size_t)k2 * 256 + nh * 128 + p * 64 + c);
      const unsigned short* vs = (const unsigned short*)&v;
      #pragma unroll
      for (int e = 0; e < 8; ++e) Bst[(p * 64 + c + e) * 40 + k2] = vs[e];
    }
    __syncthreads();
    #pragma unroll
    for (int nt = 0; nt < 8; ++nt){
      short8 bf = *(const short8*)&Bst[(16 * nt + r) * 40 + q * 8];
      acc0[nh * 8 + nt] = __builtin_amdgcn_mfma_f32_16x16x32_bf16(xa0, bf, acc0[nh * 8 + nt], 0, 0, 0);
      acc1[nh * 8 + nt] = __builtin_amdgcn_mfma_f32_16x16x32_bf16(xa1, bf, acc1[nh * 8 + nt], 0, 0, 0);
    }
  }
  __syncthreads();
  #pragma unroll
  for (int nt = 0; nt < 16; ++nt)
    #pragma unroll
    for (int i = 0; i < 4; ++i){
      HAs[(16 * w       + q * 4 + i) * 264 + 16 * nt + r] = f2b(acc0[nt][i]);
      HAs[(16 * (w + 4) + q * 4 + i) * 264 + 16 * nt + r] = f2b(acc1[nt][i]);
    }
  __syncthreads();

  auto attn256 = [&](int asoff, int adoff){
    float4 as4 = *(const float4*)(Wbuf + asoff + 4 * lane);
    float4 ad4 = *(const float4*)(Wbuf + adoff + 4 * lane);
    for (int it = 0; it < 32; ++it){
      int n = it * 4 + w;
      const unsigned short* hp = &HAs[n * 264 + 4 * lane];
      float e0 = b2f(hp[0]), e1 = b2f(hp[1]), e2 = b2f(hp[2]), e3 = b2f(hp[3]);
      float vs = e0 * as4.x + e1 * as4.y + e2 * as4.z + e3 * as4.w;
      float vd = e0 * ad4.x + e1 * ad4.y + e2 * ad4.z + e3 * ad4.w;
      #pragma unroll
      for (int m = 8; m >= 1; m >>= 1){ vs += __shfl_xor(vs, m); vd += __shfl_xor(vd, m); }
      if ((lane & 15) == 0){ ALSs[n * 4 + (lane >> 4)] = vs; ALDs[n * 4 + (lane >> 4)] = vd; }
    }
    __syncthreads();
    for (int pass = 0; pass < 2; ++pass){
      int jid = pass * 256 + tid;
      int n = jid >> 2, h = jid & 3;
      float aldv = ALDs[n * 4 + h];
      int rs = rowL[n], re = rowL[n + 1];
      float mx = -3e38f, den = 0.f;
      for (int j = rs; j < re; j += 4){
        int cnt = re - j;
        int i1 = j + (cnt > 1 ? 1 : 0);
        int i2 = j + (cnt > 2 ? 2 : 0);
        int i3 = j + (cnt > 3 ? 3 : 0);
        int s0 = srcL[j], s1 = srcL[i1], s2 = srcL[i2], s3 = srcL[i3];
        float v0 = ALSs[s0 * 4 + h] + aldv; v0 = v0 > 0.f ? v0 : 0.2f * v0;
        float v1 = ALSs[s1 * 4 + h] + aldv; v1 = v1 > 0.f ? v1 : 0.2f * v1;
        float v2 = ALSs[s2 * 4 + h] + aldv; v2 = v2 > 0.f ? v2 : 0.2f * v2;
        float v3 = ALSs[s3 * 4 + h] + aldv; v3 = v3 > 0.f ? v3 : 0.2f * v3;
        if (v0 > mx){ den = den * __expf(mx - v0) + 1.f; mx = v0; } else den += __expf(v0 - mx);
        if (cnt > 1){ if (v1 > mx){ den = den * __expf(mx - v1) + 1.f; mx = v1; } else den += __expf(v1 - mx); }
        if (cnt > 2){ if (v2 > mx){ den = den * __expf(mx - v2) + 1.f; mx = v2; } else den += __expf(v2 - mx); }
        if (cnt > 3){ if (v3 > mx){ den = den * __expf(mx - v3) + 1.f; mx = v3; } else den += __expf(v3 - mx); }
      }
      float iden = 1.f / (den + 1e-16f);
      for (int j = rs; j < re; j += 4){
        int cnt = re - j;
        int i1 = j + (cnt > 1 ? 1 : 0);
        int i2 = j + (cnt > 2 ? 2 : 0);
        int i3 = j + (cnt > 3 ? 3 : 0);
        int s0 = srcL[j], s1 = srcL[i1], s2 = srcL[i2], s3 = srcL[i3];
        float v0 = ALSs[s0 * 4 + h] + aldv; v0 = v0 > 0.f ? v0 : 0.2f * v0;
        float v1 = ALSs[s1 * 4 + h] + aldv; v1 = v1 > 0.f ? v1 : 0.2f * v1;
        float v2 = ALSs[s2 * 4 + h] + aldv; v2 = v2 > 0.f ? v2 : 0.2f * v2;
        float v3 = ALSs[s3 * 4 + h] + aldv; v3 = v3 > 0.f ? v3 : 0.2f * v3;
        union { _Float16 hh; unsigned short s; } o0, o1, o2, o3;
        o0.hh = (_Float16)(__expf(v0 - mx) * iden);
        o1.hh = (_Float16)(__expf(v1 - mx) * iden);
        o2.hh = (_Float16)(__expf(v2 - mx) * iden);
        o3.hh = (_Float16)(__expf(v3 - mx) * iden);
        AWs[j * 4 + h] = o0.s; AWs[i1 * 4 + h] = o1.s;   // pad indices rewrite same slot — harmless
        AWs[i2 * 4 + h] = o2.s; AWs[i3 * 4 + h] = o3.s;
      }
    }
    __syncthreads();
  };
  auto agg256 = [&](int boff){
    int f4 = lane * 4;
    int h = lane >> 4;
    float4 bz = *(const float4*)(Wbuf + boff + f4);
    for (int n = w; n < 128; n += 4){
      int rs = rowL[n], re = rowL[n + 1];
      float A0 = 0, A1 = 0, A2 = 0, A3 = 0;
      for (int j = rs; j < re; j += 4){
        int cnt = re - j;
        int i1 = j + (cnt > 1 ? 1 : 0);
        int i2 = j + (cnt > 2 ? 2 : 0);
        int i3 = j + (cnt > 3 ? 3 : 0);
        int s0 = srcL[j], s1 = srcL[i1], s2 = srcL[i2], s3 = srcL[i3];
        float w0 = h2f(AWs[j * 4 + h]);
        float w1 = cnt > 1 ? h2f(AWs[i1 * 4 + h]) : 0.f;
        float w2 = cnt > 2 ? h2f(AWs[i2 * 4 + h]) : 0.f;
        float w3 = cnt > 3 ? h2f(AWs[i3 * 4 + h]) : 0.f;
        const unsigned short* p0 = &HAs[s0 * 264 + f4];
        const unsigned short* p1 = &HAs[s1 * 264 + f4];
        const unsigned short* p2 = &HAs[s2 * 264 + f4];
        const unsigned short* p3 = &HAs[s3 * 264 + f4];
        A0 += w0 * b2f(p0[0]) + w1 * b2f(p1[0]) + w2 * b2f(p2[0]) + w3 * b2f(p3[0]);
        A1 += w0 * b2f(p0[1]) + w1 * b2f(p1[1]) + w2 * b2f(p2[1]) + w3 * b2f(p3[1]);
        A2 += w0 * b2f(p0[2]) + w1 * b2f(p1[2]) + w2 * b2f(p2[2]) + w3 * b2f(p3[2]);
        A3 += w0 * b2f(p0[3]) + w1 * b2f(p1[3]) + w2 * b2f(p2[3]) + w3 * b2f(p3[3]);
      }
      A0 += bz.x; A1 += bz.y; A2 += bz.z; A3 += bz.w;
      unsigned short o0 = f2b(A0 > 0.f ? A0 : 0.f);
      unsigned short o1 = f2b(A1 > 0.f ? A1 : 0.f);
      unsigned short o2 = f2b(A2 > 0.f ? A2 : 0.f);
      unsigned short o3 = f2b(A3 > 0.f ? A3 : 0.f);
      uint2 pk; pk.x = (unsigned int)o0 | ((unsigned int)o1 << 16);
      pk.y = (unsigned int)o2 | ((unsigned int)o3 << 16);
      *(uint2*)&HBs[n * 264 + f4] = pk;
    }
    __syncthreads();
  };

  attn256(WOFF_G0AS, WOFF_G0AD);
  agg256(WOFF_G0B);

  //======== Layer 1 GEMM ========
  #pragma unroll
  for (int i = 0; i < 16; ++i){ acc0[i] = (float4v){0,0,0,0}; acc1[i] = (float4v){0,0,0,0}; }
  for (int kc = 0; kc < 256; kc += 32){
    short8 a0 = *(const short8*)&HBs[(16 * w       + r) * 264 + kc + q * 8];
    short8 a1 = *(const short8*)&HBs[(16 * (w + 4) + r) * 264 + kc + q * 8];
    for (int nh = 0; nh < 2; ++nh){
      __syncthreads();
      #pragma unroll
      for (int p = 0; p < 2; ++p){
        int k2 = tid >> 3, c = (tid & 7) * 8;
        uint4 v = *(const uint4*)(BBF + BOFF_G1 + (size_t)(kc + k2) * 256 + nh * 128 + p * 64 + c);
        const unsigned short* vs = (const unsigned short*)&v;
        #pragma unroll
        for (int e = 0; e < 8; ++e) Bst[(p * 64 + c + e) * 40 + k2] = vs[e];
      }
      __syncthreads();
      #pragma unroll
      for (int nt = 0; nt < 8; ++nt){
        short8 bf = *(const short8*)&Bst[(16 * nt + r) * 40 + q * 8];
        acc0[nh * 8 + nt] = __builtin_amdgcn_mfma_f32_16x16x32_bf16(a0, bf, acc0[nh * 8 + nt], 0, 0, 0);
        acc1[nh * 8 + nt] = __builtin_amdgcn_mfma_f32_16x16x32_bf16(a1, bf, acc1[nh * 8 + nt], 0, 0, 0);
      }
    }
  }
  __syncthreads();
  #pragma unroll
  for (int nt = 0; nt < 16; ++nt)
    #pragma unroll
    for (int i = 0; i < 4; ++i){
      HAs[(16 * w       + q * 4 + i) * 264 + 16 * nt + r] = f2b(acc0[nt][i]);
      HAs[(16 * (w + 4) + q * 4 + i) * 264 + 16 * nt + r] = f2b(acc1[nt][i]);
    }
  __syncthreads();

  attn256(WOFF_G1AS, WOFF_G1AD);
  agg256(WOFF_G1B);

  //======== Layer 2 GEMM ========
  #pragma unroll
  for (int i = 0; i < 4; ++i){ acc0[i] = (float4v){0,0,0,0}; acc1[i] = (float4v){0,0,0,0}; }
  for (int kc = 0; kc < 256; kc += 32){
    short8 a0 = *(const short8*)&HBs[(16 * w       + r) * 264 + kc + q * 8];
    short8 a1 = *(const short8*)&HBs[(16 * (w + 4) + r) * 264 + kc + q * 8];
    __syncthreads();
    {
      int k2 = tid >> 3, c = (tid & 7) * 8;
      uint4 v = *(const uint4*)(BBF + BOFF_G2 + (size_t)(kc + k2) * 64 + c);
      const unsigned short* vs = (const unsigned short*)&v;
      #pragma unroll
      for (int e = 0; e < 8; ++e) Bst[(c + e) * 40 + k2] = vs[e];
    }
    __syncthreads();
    #pragma unroll
    for (int nt = 0; nt < 4; ++nt){
      short8 bf = *(const short8*)&Bst[(16 * nt + r) * 40 + q * 8];
      acc0[nt] = __builtin_amdgcn_mfma_f32_16x16x32_bf16(a0, bf, acc0[nt], 0, 0, 0);
      acc1[nt] = __builtin_amdgcn_mfma_f32_16x16x32_bf16(a1, bf, acc1[nt], 0, 0, 0);
    }
  }
  __syncthreads();
  #pragma unroll
  for (int nt = 0; nt < 4; ++nt)
    #pragma unroll
    for (int i = 0; i < 4; ++i){
      HAs[(16 * w       + q * 4 + i) * 264 + 16 * nt + r] = f2b(acc0[nt][i]);
      HAs[(16 * (w + 4) + q * 4 + i) * 264 + 16 * nt + r] = f2b(acc1[nt][i]);
    }
  __syncthreads();

  //======== Layer 2 attention + agg + pool ========
  {
    float asv = Wbuf[WOFF_G2AS + lane];
    float adv = Wbuf[WOFF_G2AD + lane];
    for (int it = 0; it < 32; ++it){
      int n = it * 4 + w;
      float e0 = b2f(HAs[n * 264 + lane]);
      float vs = e0 * asv, vd = e0 * adv;
      #pragma unroll
      for (int m = 32; m >= 1; m >>= 1){ vs += __shfl_xor(vs, m); vd += __shfl_xor(vd, m); }
      if (lane == 0){ ALSs[n] = vs; ALDs[n] = vd; }
    }
    __syncthreads();
    if (tid < 128){
      int n = tid;
      float aldv = ALDs[n];
      int rs = rowL[n], re = rowL[n + 1];
      float mx = -3e38f, den = 0.f;
      for (int j = rs; j < re; j += 4){
        int cnt = re - j;
        int i1 = j + (cnt > 1 ? 1 : 0);
        int i2 = j + (cnt > 2 ? 2 : 0);
        int i3 = j + (cnt > 3 ? 3 : 0);
        int s0 = srcL[j], s1 = srcL[i1], s2 = srcL[i2], s3 = srcL[i3];
        float v0 = ALSs[s0] + aldv; v0 = v0 > 0.f ? v0 : 0.2f * v0;
        float v1 = ALSs[s1] + aldv; v1 = v1 > 0.f ? v1 : 0.2f * v1;
        float v2 = ALSs[s2] + aldv; v2 = v2 > 0.f ? v2 : 0.2f * v2;
        float v3 = ALSs[s3] + aldv; v3 = v3 > 0.f ? v3 : 0.2f * v3;
        if (v0 > mx){ den = den * __expf(mx - v0) + 1.f; mx = v0; } else den += __expf(v0 - mx);
        if (cnt > 1){ if (v1 > mx){ den = den * __expf(mx - v1) + 1.f; mx = v1; } else den += __expf(v1 - mx); }
        if (cnt > 2){ if (v2 > mx){ den = den * __expf(mx - v2) + 1.f; mx = v2; } else den += __expf(v2 - mx); }
        if (cnt > 3){ if (v3 > mx){ den = den * __expf(mx - v3) + 1.f; mx = v3; } else den += __expf(v3 - mx); }
      }
      float iden = 1.f / (den + 1e-16f);
      for (int j = rs; j < re; j += 4){
        int cnt = re - j;
        int i1 = j + (cnt > 1 ? 1 : 0);
        int i2 = j + (cnt > 2 ? 2 : 0);
        int i3 = j + (cnt > 3 ? 3 : 0);
        int s0 = srcL[j], s1 = srcL[i1], s2 = srcL[i2], s3 = srcL[i3];
        float v0 = ALSs[s0] + aldv; v0 = v0 > 0.f ? v0 : 0.2f * v0;
        float v1 = ALSs[s1] + aldv; v1 = v1 > 0.f ? v1 : 0.2f * v1;
        float v2 = ALSs[s2] + aldv; v2 = v2 > 0.f ? v2 : 0.2f * v2;
        float v3 = ALSs[s3] + aldv; v3 = v3 > 0.f ? v3 : 0.2f * v3;
        union { _Float16 hh; unsigned short s; } o0, o1, o2, o3;
        o0.hh = (_Float16)(__expf(v0 - mx) * iden);
        o1.hh = (_Float16)(__expf(v1 - mx) * iden);
        o2.hh = (_Float16)(__expf(v2 - mx) * iden);
        o3.hh = (_Float16)(__expf(v3 - mx) * iden);
        AWs[j] = o0.s; AWs[i1] = o1.s; AWs[i2] = o2.s; AWs[i3] = o3.s;
      }
    }
    __syncthreads();
    {
      int d = lane;
      float bz = Wbuf[WOFF_G2B + d];
      for (int n = w; n < 128; n += 4){
        int rs = rowL[n], re = rowL[n + 1];
        float A0 = 0.f;
        for (int j = rs; j < re; j += 4){
          int cnt = re - j;
          int i1 = j + (cnt > 1 ? 1 : 0);
          int i2 = j + (cnt > 2 ? 2 : 0);
          int i3 = j + (cnt > 3 ? 3 : 0);
          int s0 = srcL[j], s1 = srcL[i1], s2 = srcL[i2], s3 = srcL[i3];
          float w0 = h2f(AWs[j]);
          float w1 = cnt > 1 ? h2f(AWs[i1]) : 0.f;
          float w2 = cnt > 2 ? h2f(AWs[i2]) : 0.f;
          float w3 = cnt > 3 ? h2f(AWs[i3]) : 0.f;
          A0 += w0 * b2f(HAs[s0 * 264 + d]) + w1 * b2f(HAs[s1 * 264 + d])
              + w2 * b2f(HAs[s2 * 264 + d]) + w3 * b2f(HAs[s3 * 264 + d]);
        }
        A0 += bz;
        HBs[n * 264 + d] = f2b(A0 > 0.f ? A0 : 0.f);
      }
    }
    __syncthreads();
    {
      int f = lane, part = w;
      float s = 0.f;
      for (int n = part * 32; n < part * 32 + 32; ++n) s += b2f(HBs[n * 264 + f]);
      ALSs[part * 64 + f] = s;
    }
    __syncthreads();
    if (tid < 64){
      float s = ALSs[tid] + ALSs[64 + tid] + ALSs[128 + tid] + ALSs[192 + tid];
      int b = g >> 6, tq = g & 63;
      XSEQ[(size_t)(tq * BSZ + b) * HIDD + tid] = f2b(s);
    }
  }
}

// ---------------- MFMA matmul for BOTH Wih GEMMs in one launch (z = dir) ----------------
__global__ __launch_bounds__(256)
void mmx2_kernel(const unsigned short* __restrict__ A,
                 const unsigned short* __restrict__ B0, const unsigned short* __restrict__ B1,
                 float* __restrict__ C0, float* __restrict__ C1, int M, int Nc, int K)
{
  __shared__ unsigned short As[64][40];
  __shared__ unsigned short Bs[64][40];
  const unsigned short* Bb = blockIdx.z ? B1 : B0;
  float* C = blockIdx.z ? C1 : C0;
  const int tid = threadIdx.x;
  const int w = tid >> 6, lane = tid & 63, q = lane >> 4, r = lane & 15;
  const int m0 = blockIdx.x * 64, n0 = blockIdx.y * 64;
  float4v acc0 = {0,0,0,0}, acc1 = {0,0,0,0}, acc2 = {0,0,0,0}, acc3 = {0,0,0,0};
  const int arow = tid >> 2, akb = (tid & 3) * 8;
  const int bk = tid >> 3, bnb = (tid & 7) * 8;
  for (int kc = 0; kc < K; kc += 32){
    int kw = K - kc; if (kw > 32) kw = 32;
    if (akb < kw){
      uint4 v = *(const uint4*)(A + (size_t)(m0 + arow) * K + kc + akb);
      *(uint4*)&As[arow][akb] = v;
    } else {
      uint4 z = {0,0,0,0}; *(uint4*)&As[arow][akb] = z;
    }
    if (bk < kw){
      uint4 v = *(const uint4*)(Bb + (size_t)(kc + bk) * Nc + n0 + bnb);
      const unsigned short* vs = (const unsigned short*)&v;
      #pragma unroll
      for (int e = 0; e < 8; ++e) Bs[bnb + e][bk] = vs[e];
    } else {
      #pragma unroll
      for (int e = 0; e < 8; ++e) Bs[bnb + e][bk] = 0;
    }
    __syncthreads();
    short8 af = *(const short8*)&As[16 * w + r][q * 8];
    short8 b0 = *(const short8*)&Bs[r][q * 8];
    short8 b1 = *(const short8*)&Bs[16 + r][q * 8];
    short8 b2 = *(const short8*)&Bs[32 + r][q * 8];
    short8 b3 = *(const short8*)&Bs[48 + r][q * 8];
    acc0 = __builtin_amdgcn_mfma_f32_16x16x32_bf16(af, b0, acc0, 0, 0, 0);
    acc1 = __builtin_amdgcn_mfma_f32_16x16x32_bf16(af, b1, acc1, 0, 0, 0);
    acc2 = __builtin_amdgcn_mfma_f32_16x16x32_bf16(af, b2, acc2, 0, 0, 0);
    acc3 = __builtin_amdgcn_mfma_f32_16x16x32_bf16(af, b3, acc3, 0, 0, 0);
    __syncthreads();
  }
  const int row = m0 + 16 * w + q * 4, col0 = n0 + r;
  #pragma unroll
  for (int i = 0; i < 4; ++i){
    size_t base = (size_t)(row + i) * Nc;
    C[base + col0]      = acc0[i];
    C[base + col0 + 16] = acc1[i];
    C[base + col0 + 32] = acc2[i];
    C[base + col0 + 48] = acc3[i];
  }
}

// ---------------- LSTM, M-split, sentinel-payload sync with PER-CONSUMER copies ----------------
__global__ __launch_bounds__(256)
void lstm12_kernel(const float* __restrict__ XF, const float* __restrict__ XB,
                   const unsigned int* __restrict__ WT,
                   const float* __restrict__ bih_f, const float* __restrict__ bhh_f,
                   const float* __restrict__ bih_b, const float* __restrict__ bhh_b,
                   unsigned int* __restrict__ HX,
                   float* __restrict__ HT)
{
  __shared__ unsigned int WL[32][256][4];
  __shared__ unsigned int h2u[512];
  __shared__ float glds[4][64][5];

  const int tid = threadIdx.x;
  const int m = blockIdx.x & 3, dir = blockIdx.x >> 2;
  const int gq = tid >> 6, jl = tid & 63;
  const int u = gq * 256 + 64 * m + jl;
  const float* Xp = dir ? XB : XF;
  const float bias = (dir ? bih_b : bih_f)[u] + (dir ? bhh_b : bhh_f)[u];
  const int ub = tid >> 6, uj = tid & 63;
  unsigned int* HXd = HX + dir * 6144;       // [slot:3][consumer:4][512]

  {
    const uint4* WT4 = (const uint4*)(WT + (dir << 17));
    #pragma unroll
    for (int kk4 = 0; kk4 < 32; ++kk4)
      *(uint4*)WL[kk4][tid] = WT4[(kk4 << 10) + u];
  }
  for (int i = tid; i < 512; i += 256) h2u[i] = 0;
  float c = 0.f;
  __syncthreads();

  float a0, a1, a2, a3;
  auto consume = [&](int kk4){
    uint4 w4 = *(const uint4*)WL[kk4][tid];
    uint4 hb0 = *(const uint4*)&h2u[0 * 128 + (kk4 << 2)];
    uint4 hb1 = *(const uint4*)&h2u[1 * 128 + (kk4 << 2)];
    uint4 hb2 = *(const uint4*)&h2u[2 * 128 + (kk4 << 2)];
    uint4 hb3 = *(const uint4*)&h2u[3 * 128 + (kk4 << 2)];
    a0 = dot2h(w4.x, hb0.x, a0); a0 = dot2h(w4.y, hb0.y, a0);
    a0 = dot2h(w4.z, hb0.z, a0); a0 = dot2h(w4.w, hb0.w, a0);
    a1 = dot2h(w4.x, hb1.x, a1); a1 = dot2h(w4.y, hb1.y, a1);
    a1 = dot2h(w4.z, hb1.z, a1); a1 = dot2h(w4.w, hb1.w, a1);
    a2 = dot2h(w4.x, hb2.x, a2); a2 = dot2h(w4.y, hb2.y, a2);
    a2 = dot2h(w4.z, hb2.z, a2); a2 = dot2h(w4.w, hb2.w, a2);
    a3 = dot2h(w4.x, hb3.x, a3); a3 = dot2h(w4.y, hb3.y, a3);
    a3 = dot2h(w4.z, hb3.z, a3); a3 = dot2h(w4.w, hb3.w, a3);
  };

  for (int t = 0; t < TT; ++t){
    const int tb = dir ? (TT - 1 - t) : t;
    const float* xr = Xp + (size_t)(tb * 4) * 1024 + u;
    a0 = bias + xr[0];
    a1 = bias + xr[1024];
    a2 = bias + xr[2048];
    a3 = bias + xr[3072];
    // Phase A: own K-chunk (peer-independent — overlaps peers' publish latency)
    #pragma unroll
    for (int i = 0; i < 8; ++i) consume(8 * m + i);
    // Phase B: fetch peer slices of h(t-1) from this WG's consumer region, poll payload
    if (t > 0 && gq > 0){
      int qp = (m + gq) & 3;
      unsigned int* S = HXd + ((t - 1) % 3) * 2048 + m * 512;
      int b2 = jl >> 5, p2 = jl & 31;
      int i1 = b2 * 128 + 32 * qp + p2;
      int i2 = (b2 + 2) * 128 + 32 * qp + p2;
      unsigned int v1, v2;
      int guard = 0;
      while ((v1 = __hip_atomic_load(&S[i1], __ATOMIC_RELAXED, __HIP_MEMORY_SCOPE_AGENT)) == SENT
             && guard < 200000){ __builtin_amdgcn_s_sleep(1); ++guard; }
      guard = 0;
      while ((v2 = __hip_atomic_load(&S[i2], __ATOMIC_RELAXED, __HIP_MEMORY_SCOPE_AGENT)) == SENT
             && guard < 200000){ __builtin_amdgcn_s_sleep(1); ++guard; }
      h2u[i1] = v1; h2u[i2] = v2;
      __hip_atomic_store(&S[i1], SENT, __ATOMIC_RELAXED, __HIP_MEMORY_SCOPE_AGENT);
      __hip_atomic_store(&S[i2], SENT, __ATOMIC_RELAXED, __HIP_MEMORY_SCOPE_AGENT);
    }
    __syncthreads();
    // Phase C: peer K-chunks
    #pragma unroll
    for (int i = 1; i < 4; ++i){
      int qp = (m + i) & 3;
      #pragma unroll
      for (int s = 0; s < 8; ++s) consume(8 * qp + s);
    }
    glds[gq][jl][0] = a0; glds[gq][jl][1] = a1;
    glds[gq][jl][2] = a2; glds[gq][jl][3] = a3;
    __syncthreads();

    float gi = glds[0][uj][ub];
    float gf = glds[1][uj][ub];
    float gg = glds[2][uj][ub];
    float go = glds[3][uj][ub];
    float si = 1.f / (1.f + __expf(-gi));
    float sf = 1.f / (1.f + __expf(-gf));
    float so = 1.f / (1.f + __expf(-go));
    float tg = 1.f - 2.f / (1.f + __expf(2.f * gg));
    c = sf * c + si * tg;
    float ch = 1.f - 2.f / (1.f + __expf(2.f * c));
    float hval = so * ch;
    if (t == TT - 1){
      HT[(size_t)(dir * 4 + ub) * RHID + (64 * m + uj)] = hval;
      break;
    }
    union { _Float16 h; unsigned short s; } uh; uh.h = (_Float16)hval;
    unsigned int own = uh.s;
    unsigned int partner = ((unsigned int)__shfl_xor((int)own, 1)) & 0xffffu;
    unsigned int* S = HXd + (t % 3) * 2048;
    if ((uj & 1) == 0){
      unsigned int v = own | (partner << 16);
      int p = uj >> 1;
      int idx = ub * 128 + 32 * m + p;
      h2u[idx] = v;
      #pragma unroll
      for (int cns = 1; cns < 4; ++cns)
        __hip_atomic_store(&S[((m + cns) & 3) * 512 + idx], v,
                           __ATOMIC_RELAXED, __HIP_MEMORY_SCOPE_AGENT);
    }
    __syncthreads();   // drains publish + clears before next step
  }
}

// ---------------- heads + Poincare projection, fp32 out ----------------
__global__ __launch_bounds__(512)
void head2_kernel(const float* __restrict__ HT,
                  const float* __restrict__ muW, const float* __restrict__ mub,
                  const float* __restrict__ lvW, const float* __restrict__ lvb,
                  float* __restrict__ out)
{
  __shared__ float feat[4][512];
  __shared__ float muv[4][64];
  __shared__ float lvv[4][64];
  int tid = threadIdx.x;
  for (int i = tid; i < 2048; i += 512){
    int rr = i >> 8, k = i & 255;
    int b = rr & 3, d = rr >> 2;
    feat[b][d * 256 + k] = HT[i];
  }
  __syncthreads();
  int w = tid >> 6, lane = tid & 63;
  for (int job = w; job < 512; job += 8){
    int j = job & 63, b = (job >> 6) & 3, mat = job >> 8;
    const float* W = (mat ? lvW : muW) + (size_t)j * 512;
    float s = 0.f;
    #pragma unroll
    for (int e = 0; e < 8; ++e) s += W[lane * 8 + e] * feat[b][lane * 8 + e];
    #pragma unroll
    for (int mm = 32; mm >= 1; mm >>= 1) s += __shfl_xor(s, mm);
    if (lane == 0){
      float v = s + (mat ? lvb[j] : mub[j]);
      if (mat) lvv[b][j] = v; else muv[b][j] = v;
    }
  }
  __syncthreads();
  if (tid < 256){
    int b = tid >> 6, j = tid & 63;
    float mu = muv[b][j];
    float sq = mu * mu;
    #pragma unroll
    for (int mm = 32; mm >= 1; mm >>= 1) sq += __shfl_xor(sq, mm);
    float nrm = sqrtf(sq);
    const float mxn = 1.0f - 4e-3f;
    if (nrm > mxn) mu = mu / nrm * mxn;
    out[b * 64 + j] = mu;
    out[256 + b * 64 + j] = lvv[b][j];
  }
}

extern "C" void kernel_launch(void* const* d_in, const int* in_sizes, int n_in,
                              void* d_out, int out_size, void* d_ws, size_t ws_size,
                              hipStream_t stream)
{
  const int* ei = (const int*)d_in[1];

  int*   ws_i    = (int*)d_ws;
  int*   dflag   = ws_i;
  float* FW   = (float*)d_ws;
  float* Wbuf = FW + FOFF_WBUF;
  float* XFp  = FW + FOFF_XFP;
  float* XBp  = FW + FOFF_XBP;
  float* HT   = FW + FOFF_HT;
  unsigned short* XSEQ = (unsigned short*)(FW + FOFF_XSEQ);
  unsigned short* Pb   = (unsigned short*)(FW + FOFF_P);
  unsigned int*   WT   = (unsigned int*)(FW + FOFF_WE);
  unsigned short* BBF  = (unsigned short*)(FW + FOFF_BBF);
  unsigned int*   HX   = (unsigned int*)(FW + FOFF_SYNC);   // 2*3*4*512 uints

  // ---- dtype sniff + fused setup ----
  sniff_kernel<<<1, 256, 0, stream>>>((const unsigned short*)d_in[2], dflag);

  CvtArgs ca;
  static const int wsz[24] = {4096,256,256,256, 65536,256,256,256, 16384,64,64,64,
                              65536,262144,1024,1024, 65536,262144,1024,1024,
                              32768,64,32768,64};
  {
    int acc = 0;
    for (int k = 0; k < 24; ++k){ ca.src[k] = d_in[2 + k]; ca.off[k] = acc; acc += wsz[k]; }
    ca.off[24] = acc;
  }
  setup_kernel<<<(SP_TOTAL + 255) / 256, 256, 0, stream>>>(ca, dflag, Wbuf, BBF, Pb, WT, d_in[0]);

  // ---- fused GAT x3 + pool (256 threads — known-good config) ----
  gatall_kernel<<<NGRAPH, 256, 0, stream>>>(Pb, BBF, Wbuf, ei, XSEQ);

  // ---- LSTM input precompute: both directions in one launch ----
  mmx2_kernel<<<dim3(4, 16, 2), 256, 0, stream>>>(XSEQ, BBF + BOFF_WF, BBF + BOFF_WB,
                                                  XFp, XBp, 256, 1024, 64);

  // ---- LSTM: sentinel-payload protocol, per-consumer copies (HX starts as SENT) ----
  hipMemsetAsync((void*)HX, 0xFF, 2 * 3 * 4 * 512 * 4, stream);
  lstm12_kernel<<<8, 256, 0, stream>>>(XFp, XBp, WT,
                                       Wbuf + WOFF_BIHF, Wbuf + WOFF_BHHF,
                                       Wbuf + WOFF_BIHB, Wbuf + WOFF_BHHB,
                                       HX, HT);

  // ---- heads + projection ----
  head2_kernel<<<1, 512, 0, stream>>>(HT, Wbuf + WOFF_MUW, Wbuf + WOFF_MUB,
                                      Wbuf + WOFF_LVW, Wbuf + WOFF_LVB, (float*)d_out);
}